// Round 8
// baseline (1208.147 us; speedup 1.0000x reference)
//
#include <hip/hip_runtime.h>
#include <hip/hip_bf16.h>
#include <cmath>

#define NSEQ 480
#define SEQN 128
#define CDIM 256
#define NH 8
#define HD 32
#define TOPM 20

typedef float f32x4 __attribute__((ext_vector_type(4)));
typedef short bf16x8 __attribute__((ext_vector_type(8)));

__device__ __forceinline__ unsigned short bf16_rn(float x) {
    unsigned int u = __float_as_uint(x);
    unsigned int r = (u + 0x7FFFu + ((u >> 16) & 1u)) >> 16;
    return (unsigned short)r;
}
__device__ __forceinline__ float bf16f(unsigned short h) {
    return __uint_as_float(((unsigned int)h) << 16);
}
__device__ __forceinline__ unsigned int okey(float v) {
    unsigned int u = __float_as_uint(v);
    return (u >> 31) ? ~u : (u | 0x80000000u);
}
__device__ __forceinline__ float okey_inv(unsigned int k) {
    return __uint_as_float((k >> 31) ? (k & 0x7FFFFFFFu) : ~k);
}
__device__ __forceinline__ unsigned pk_bf16(float a, float b) {
    union { __hip_bfloat162 h; unsigned u; } cv;
    cv.h = __float22bfloat162_rn(make_float2(a, b));
    return cv.u;
}
__device__ __forceinline__ void unpack_bf16x8(uint4 u, float* o) {
    o[0] = bf16f((unsigned short)(u.x & 0xffffu)); o[1] = bf16f((unsigned short)(u.x >> 16));
    o[2] = bf16f((unsigned short)(u.y & 0xffffu)); o[3] = bf16f((unsigned short)(u.y >> 16));
    o[4] = bf16f((unsigned short)(u.z & 0xffffu)); o[5] = bf16f((unsigned short)(u.z >> 16));
    o[6] = bf16f((unsigned short)(u.w & 0xffffu)); o[7] = bf16f((unsigned short)(u.w >> 16));
}

// ---------------------------------------------------------------------------
// K1: transpose (B, C, N) -> (B, N, C), add pos_embed, emit split-bf16 planes
__global__ __launch_bounds__(256) void prep_kernel(const float* __restrict__ RW,
                                                   const float* __restrict__ POS,
                                                   unsigned short* __restrict__ XH,
                                                   unsigned short* __restrict__ XL) {
    int b = blockIdx.x, n0 = blockIdx.y * 32, c0 = blockIdx.z * 32;
    __shared__ float tile[32][33];
    int tx = threadIdx.x & 31, ty = threadIdx.x >> 5;
#pragma unroll
    for (int jj = 0; jj < 4; ++jj) {
        int c = c0 + ty + 8 * jj;
        tile[ty + 8 * jj][tx] = RW[((size_t)b * CDIM + c) * SEQN + n0 + tx];
    }
    __syncthreads();
#pragma unroll
    for (int jj = 0; jj < 4; ++jj) {
        int n = n0 + ty + 8 * jj;
        int c = c0 + tx;
        float val = tile[tx][ty + 8 * jj] + POS[n * CDIM + c];
        unsigned short hi = bf16_rn(val);
        size_t idx = (size_t)b * SEQN * CDIM + n * CDIM + c;
        XH[idx] = hi;
        XL[idx] = bf16_rn(val - bf16f(hi));
    }
}

// ---------------------------------------------------------------------------
// K1b: both weight splits for one layer in one launch.
__global__ __launch_bounds__(256) void wsplit2_kernel(
    const float* __restrict__ Wq, const float* __restrict__ Wp,
    unsigned short* __restrict__ QH, unsigned short* __restrict__ QL,
    unsigned short* __restrict__ PH, unsigned short* __restrict__ PL) {
    int k0 = blockIdx.x * 32;
    int yy = blockIdx.y;
    const float* W;
    unsigned short *WH, *WL;
    int ncols, j0;
    if (yy < 24) { W = Wq; WH = QH; WL = QL; ncols = 768; j0 = yy * 32; }
    else         { W = Wp; WH = PH; WL = PL; ncols = 256; j0 = (yy - 24) * 32; }
    __shared__ float tile[32][33];
    int tx = threadIdx.x & 31, ty = threadIdx.x >> 5;
#pragma unroll
    for (int jj = 0; jj < 4; ++jj)
        tile[ty + 8 * jj][tx] = W[(size_t)(k0 + ty + 8 * jj) * ncols + j0 + tx];
    __syncthreads();
#pragma unroll
    for (int jj = 0; jj < 4; ++jj) {
        float v = tile[tx][ty + 8 * jj];
        unsigned short hi = bf16_rn(v);
        unsigned short lo = bf16_rn(v - bf16f(hi));
        size_t idx = (size_t)(j0 + ty + 8 * jj) * 256 + k0 + tx;
        WH[idx] = hi;
        WL[idx] = lo;
    }
}

// ---------------------------------------------------------------------------
// K2: fused qkv + exact top-20 attention.
// 256 threads / 4 waves; TWO blocks per (b,h), each owning 64 q-rows
// (wave = 16 q-rows).  Each block computes k,v for all 128 tokens
// (cooperative, duplicated across the pair) + its own q rows.
// Register peak ~halved vs 32-row waves (sacc[8] = 32 AGPR) -> target
// 5 waves/SIMD under the (256,4) 128-reg budget.  LDS = 32 KiB -> 5 blocks/CU.
__global__ __launch_bounds__(256, 4) void attn_kernel(
    const unsigned short* __restrict__ XHi, const unsigned short* __restrict__ XLo,
    unsigned short* __restrict__ OH, unsigned short* __restrict__ OL,
    const unsigned short* __restrict__ WtHi, const unsigned short* __restrict__ WtLo,
    const float* __restrict__ BIAS) {
    const int bid2 = blockIdx.x;
    const int half = bid2 / (NSEQ * NH);
    const int s = bid2 - half * (NSEQ * NH);
    const int h = (s >> 3) & 7;
    const int b = ((s >> 6) << 3) | (s & 7);
    const float scale = 0.17677669529663687f;  // 1/sqrt(32)

    // q: 64 rows (this block's), row-major [64][32], swizzle d^(((lrow>>1)&3)<<3)
    // k: [128][32] same swizzle on global token; vT: [32][128], t^((d&7)<<3)
    __shared__ unsigned short qh[64 * HD], ql[64 * HD];
    __shared__ unsigned short kh[SEQN * HD], kl[SEQN * HD];
    __shared__ unsigned short vh[HD * SEQN];

    const int tid = threadIdx.x;
    const int w = tid >> 6;    // wave 0..3
    const int l = tid & 63;
    const int l15 = l & 15;
    const int sct = l >> 4;
    const size_t xbase = (size_t)b * SEQN * CDIM;

    // ================= Phase 1: QKV via MFMA =================
    // k,v: wave covers tokens [w*32, w*32+32).  q: rows half*64 + w*16 + ...
    f32x4 acck[2][2], accv[2][2], accq[2];
#pragma unroll
    for (int mi = 0; mi < 2; ++mi)
#pragma unroll
        for (int ni = 0; ni < 2; ++ni) {
            acck[mi][ni] = (f32x4){0.f, 0.f, 0.f, 0.f};
            accv[mi][ni] = (f32x4){0.f, 0.f, 0.f, 0.f};
        }
    accq[0] = (f32x4){0.f, 0.f, 0.f, 0.f};
    accq[1] = (f32x4){0.f, 0.f, 0.f, 0.f};

    const int qrow_g = half * 64 + w * 16 + l15;  // global q row (A-frag)

#pragma unroll 2
    for (int ks = 0; ks < 8; ++ks) {
        const int kb = ks * 32;
        bf16x8 ahi[2], alo[2];
#pragma unroll
        for (int mi = 0; mi < 2; ++mi) {
            int row = w * 32 + mi * 16 + l15;
            size_t off = xbase + row * CDIM + kb + sct * 8;
            ahi[mi] = *reinterpret_cast<const bf16x8*>(XHi + off);
            alo[mi] = *reinterpret_cast<const bf16x8*>(XLo + off);
        }
        bf16x8 aqh8, aql8;
        {
            size_t off = xbase + qrow_g * CDIM + kb + sct * 8;
            aqh8 = *reinterpret_cast<const bf16x8*>(XHi + off);
            aql8 = *reinterpret_cast<const bf16x8*>(XLo + off);
        }
#pragma unroll
        for (int ni = 0; ni < 2; ++ni) {
            const int dj = ni * 16 + l15;
            // k (split, 3-term)
            {
                int woff = (256 + h * HD + dj) * 256 + kb + sct * 8;
                bf16x8 bh = *reinterpret_cast<const bf16x8*>(WtHi + woff);
                bf16x8 bl = *reinterpret_cast<const bf16x8*>(WtLo + woff);
#pragma unroll
                for (int mi = 0; mi < 2; ++mi) {
                    acck[mi][ni] = __builtin_amdgcn_mfma_f32_16x16x32_bf16(ahi[mi], bh, acck[mi][ni], 0, 0, 0);
                    acck[mi][ni] = __builtin_amdgcn_mfma_f32_16x16x32_bf16(ahi[mi], bl, acck[mi][ni], 0, 0, 0);
                    acck[mi][ni] = __builtin_amdgcn_mfma_f32_16x16x32_bf16(alo[mi], bh, acck[mi][ni], 0, 0, 0);
                }
            }
            // v (single bf16)
            {
                int woff = (512 + h * HD + dj) * 256 + kb + sct * 8;
                bf16x8 bh = *reinterpret_cast<const bf16x8*>(WtHi + woff);
#pragma unroll
                for (int mi = 0; mi < 2; ++mi)
                    accv[mi][ni] = __builtin_amdgcn_mfma_f32_16x16x32_bf16(ahi[mi], bh, accv[mi][ni], 0, 0, 0);
            }
            // q (split, 3-term) for this block's rows
            {
                int woff = (h * HD + dj) * 256 + kb + sct * 8;
                bf16x8 bh = *reinterpret_cast<const bf16x8*>(WtHi + woff);
                bf16x8 bl = *reinterpret_cast<const bf16x8*>(WtLo + woff);
                accq[ni] = __builtin_amdgcn_mfma_f32_16x16x32_bf16(aqh8, bh, accq[ni], 0, 0, 0);
                accq[ni] = __builtin_amdgcn_mfma_f32_16x16x32_bf16(aqh8, bl, accq[ni], 0, 0, 0);
                accq[ni] = __builtin_amdgcn_mfma_f32_16x16x32_bf16(aql8, bh, accq[ni], 0, 0, 0);
            }
        }
    }
    // epilogues
#pragma unroll
    for (int ni = 0; ni < 2; ++ni) {
        const int dcol = ni * 16 + l15;
        // k
        {
            float bias = BIAS[256 + h * HD + dcol];
#pragma unroll
            for (int mi = 0; mi < 2; ++mi)
#pragma unroll
                for (int r = 0; r < 4; ++r) {
                    float v = acck[mi][ni][r] + bias;
                    unsigned short hi = bf16_rn(v);
                    int token = w * 32 + mi * 16 + sct * 4 + r;
                    int idx = token * HD + (dcol ^ (((token >> 1) & 3) << 3));
                    kh[idx] = hi;
                    kl[idx] = bf16_rn(v - bf16f(hi));
                }
        }
        // v (packed pairs)
        {
            float bias = BIAS[512 + h * HD + dcol];
#pragma unroll
            for (int mi = 0; mi < 2; ++mi) {
                int tb = w * 32 + mi * 16 + sct * 4;
                float v0 = accv[mi][ni][0] + bias, v1 = accv[mi][ni][1] + bias;
                float v2 = accv[mi][ni][2] + bias, v3 = accv[mi][ni][3] + bias;
                unsigned pA = pk_bf16(v0, v1), pB = pk_bf16(v2, v3);
                int c0i = tb ^ ((dcol & 7) << 3);
                *reinterpret_cast<uint2*>(&vh[dcol * SEQN + c0i]) = make_uint2(pA, pB);
            }
        }
        // q (local 64-row region)
        {
            float bias = BIAS[h * HD + dcol];
#pragma unroll
            for (int r = 0; r < 4; ++r) {
                float v = (accq[ni][r] + bias) * scale;
                unsigned short hi = bf16_rn(v);
                int lrow = w * 16 + sct * 4 + r;
                int idx = lrow * HD + (dcol ^ (((lrow >> 1) & 3) << 3));
                qh[idx] = hi;
                ql[idx] = bf16_rn(v - bf16f(hi));
            }
        }
    }
    __syncthreads();

    // ================= Phase 2: S^T = K·Q^T, in-register softmax ============
    f32x4 sacc[8];
#pragma unroll
    for (int mi = 0; mi < 8; ++mi) sacc[mi] = (f32x4){0.f, 0.f, 0.f, 0.f};

    const int lrow = w * 16 + l15;
    const int qoff = lrow * HD + ((sct * 8) ^ (((lrow >> 1) & 3) << 3));
    bf16x8 qfh = *reinterpret_cast<const bf16x8*>(qh + qoff);
    bf16x8 qfl = *reinterpret_cast<const bf16x8*>(ql + qoff);
    __builtin_amdgcn_s_setprio(1);
#pragma unroll
    for (int mi = 0; mi < 8; ++mi) {
        int krow = (mi << 4) + l15;
        int off = krow * HD + ((sct * 8) ^ (((krow >> 1) & 3) << 3));
        bf16x8 kfh = *reinterpret_cast<const bf16x8*>(kh + off);
        bf16x8 kfl = *reinterpret_cast<const bf16x8*>(kl + off);
        sacc[mi] = __builtin_amdgcn_mfma_f32_16x16x32_bf16(kfh, qfh, sacc[mi], 0, 0, 0);
        sacc[mi] = __builtin_amdgcn_mfma_f32_16x16x32_bf16(kfh, qfl, sacc[mi], 0, 0, 0);
        sacc[mi] = __builtin_amdgcn_mfma_f32_16x16x32_bf16(kfl, qfh, sacc[mi], 0, 0, 0);
    }
    __builtin_amdgcn_s_setprio(0);
#pragma unroll
    for (int mi = 0; mi < 8; ++mi)
#pragma unroll
        for (int r = 0; r < 4; ++r)
            sacc[mi][r] = __uint_as_float(okey(sacc[mi][r]));

    // row max and min (monotone in key domain)
    unsigned int km = 0u, kn = 0xFFFFFFFFu;
#pragma unroll
    for (int mi = 0; mi < 8; ++mi)
#pragma unroll
        for (int r = 0; r < 4; ++r) {
            unsigned int u = __float_as_uint(sacc[mi][r]);
            km = max(km, u);
            kn = min(kn, u);
        }
    km = max(km, (unsigned int)__shfl_xor((int)km, 16));
    km = max(km, (unsigned int)__shfl_xor((int)km, 32));
    kn = min(kn, (unsigned int)__shfl_xor((int)kn, 16));
    kn = min(kn, (unsigned int)__shfl_xor((int)kn, 32));
    float mx = okey_inv(km);

    // exact top-20 threshold: bracketed bisection from [kn, km+1], early exit
    unsigned p0;
    {
        unsigned lo = kn, hi = km + 1u, th = km;
        int dn = 0;
#pragma unroll 1
        for (int it = 0; it < 34; ++it) {
            if (__all(dn)) break;
            unsigned mid = lo + ((hi - lo) >> 1);
            int c = 0;
#pragma unroll
            for (int mi = 0; mi < 8; ++mi)
#pragma unroll
                for (int r = 0; r < 4; ++r)
                    c += (__float_as_uint(sacc[mi][r]) >= mid) ? 1 : 0;
            c += __shfl_xor(c, 16);
            c += __shfl_xor(c, 32);
            if (!dn) {
                if (c == TOPM) { th = mid; dn = 1; }
                else if (hi - lo <= 1u) { th = lo; dn = 1; }
                else if (c > TOPM) lo = mid;
                else hi = mid;
            }
        }
        p0 = th;
    }

    // masked exp (unnormalized) + row sum
    float s0 = 0.f;
#pragma unroll
    for (int mi = 0; mi < 8; ++mi)
#pragma unroll
        for (int r = 0; r < 4; ++r) {
            unsigned int u0 = __float_as_uint(sacc[mi][r]);
            float e0 = (u0 >= p0) ? __expf(okey_inv(u0) - mx) : 0.f;
            sacc[mi][r] = e0;
            s0 += e0;
        }
    s0 += __shfl_xor(s0, 16);
    s0 += __shfl_xor(s0, 32);
    float i0 = 1.f / s0;

    // pack weights to bf16 pairs
    unsigned w16a[8][2];
#pragma unroll
    for (int mi = 0; mi < 8; ++mi)
#pragma unroll
        for (int p = 0; p < 2; ++p)
            w16a[mi][p] = pk_bf16(sacc[mi][2 * p], sacc[mi][2 * p + 1]);

    // ================= Phase 3: O = P·V via MFMA ==============
    f32x4 oacc[2];
    oacc[0] = (f32x4){0.f, 0.f, 0.f, 0.f};
    oacc[1] = (f32x4){0.f, 0.f, 0.f, 0.f};

#pragma unroll
    for (int k = 0; k < 4; ++k) {
        bf16x8 bvh[2];
#pragma unroll
        for (int nio = 0; nio < 2; ++nio) {
            int drow = (nio << 4) + l15;
            int off = drow * SEQN + ((k * 32 + sct * 8) ^ ((drow & 7) << 3));
            bvh[nio] = *reinterpret_cast<const bf16x8*>(vh + off);
        }
        union { unsigned u[4]; bf16x8 v8; } aw;
#pragma unroll
        for (int j = 0; j < 4; ++j) {
            int src = l15 + ((sct & 1) << 5) + ((j >> 1) << 4);
            unsigned a0 = (unsigned)__shfl((int)w16a[2 * k][j & 1], src);
            unsigned a1 = (unsigned)__shfl((int)w16a[2 * k + 1][j & 1], src);
            aw.u[j] = (sct >= 2) ? a1 : a0;
        }
        __builtin_amdgcn_s_setprio(1);
#pragma unroll
        for (int nio = 0; nio < 2; ++nio)
            oacc[nio] = __builtin_amdgcn_mfma_f32_16x16x32_bf16(aw.v8, bvh[nio], oacc[nio], 0, 0, 0);
        __builtin_amdgcn_s_setprio(0);
    }
    float invO[4];
#pragma unroll
    for (int r = 0; r < 4; ++r) invO[r] = __shfl(i0, sct * 4 + r);
#pragma unroll
    for (int nio = 0; nio < 2; ++nio)
#pragma unroll
        for (int r = 0; r < 4; ++r) {
            int token = half * 64 + w * 16 + sct * 4 + r;
            int d = (nio << 4) + l15;
            size_t idx = ((size_t)b * SEQN + token) * CDIM + h * HD + d;
            float v = oacc[nio][r] * invO[r];
            unsigned short hi = bf16_rn(v);
            OH[idx] = hi;
            OL[idx] = bf16_rn(v - bf16f(hi));
        }
}

// ---------------------------------------------------------------------------
// K3: MFMA proj GEMM + bias + residual + LayerNorm, 32 tokens per block.
__global__ __launch_bounds__(256, 4) void projln_kernel(
    const unsigned short* __restrict__ OHp, const unsigned short* __restrict__ OLp,
    unsigned short* __restrict__ XH, unsigned short* __restrict__ XL,
    const unsigned short* __restrict__ W2H, const unsigned short* __restrict__ W2L,
    const float* __restrict__ PB, const float* __restrict__ G,
    const float* __restrict__ BB) {
    const int b = blockIdx.x;
    const int t0 = blockIdx.y * 32;
    __shared__ float vals[32 * 289];
    __shared__ float part[8][32][2];

    const int tid = threadIdx.x;
    const int w = tid >> 6;
    const int l = tid & 63;
    const int l15 = l & 15;
    const int sct = l >> 4;

    f32x4 acc[2][4];
#pragma unroll
    for (int mi = 0; mi < 2; ++mi)
#pragma unroll
        for (int ni = 0; ni < 4; ++ni) acc[mi][ni] = (f32x4){0.f, 0.f, 0.f, 0.f};

    const size_t obase = ((size_t)b * SEQN + t0) * CDIM;
#pragma unroll 2
    for (int ks = 0; ks < 8; ++ks) {
        const int kb = ks * 32;
        bf16x8 ahi[2], alo[2];
#pragma unroll
        for (int mi = 0; mi < 2; ++mi) {
            size_t off = obase + (size_t)(mi * 16 + l15) * CDIM + kb + sct * 8;
            ahi[mi] = *reinterpret_cast<const bf16x8*>(OHp + off);
            alo[mi] = *reinterpret_cast<const bf16x8*>(OLp + off);
        }
#pragma unroll
        for (int ni = 0; ni < 4; ++ni) {
            int j = w * 64 + ni * 16 + l15;
            int woff = j * 256 + kb + sct * 8;
            bf16x8 bh = *reinterpret_cast<const bf16x8*>(W2H + woff);
            bf16x8 bl = *reinterpret_cast<const bf16x8*>(W2L + woff);
#pragma unroll
            for (int mi = 0; mi < 2; ++mi) {
                acc[mi][ni] = __builtin_amdgcn_mfma_f32_16x16x32_bf16(ahi[mi], bh, acc[mi][ni], 0, 0, 0);
                acc[mi][ni] = __builtin_amdgcn_mfma_f32_16x16x32_bf16(ahi[mi], bl, acc[mi][ni], 0, 0, 0);
                acc[mi][ni] = __builtin_amdgcn_mfma_f32_16x16x32_bf16(alo[mi], bh, acc[mi][ni], 0, 0, 0);
            }
        }
    }
#pragma unroll
    for (int ni = 0; ni < 4; ++ni) {
        int j = w * 64 + ni * 16 + l15;
        float bias = PB[j];
#pragma unroll
        for (int mi = 0; mi < 2; ++mi)
#pragma unroll
            for (int r = 0; r < 4; ++r) {
                int tok = mi * 16 + sct * 4 + r;
                vals[tok * 289 + j] = acc[mi][ni][r] + bias;
            }
    }
    __syncthreads();

    const int row = tid & 31;
    const int cc = tid >> 5;
    const size_t rbase = ((size_t)b * SEQN + t0 + row) * CDIM + cc * 32;
    float v[32];
    {
        float ps = 0.f, pq = 0.f;
#pragma unroll
        for (int q = 0; q < 4; ++q) {
            uint4 hb = *reinterpret_cast<const uint4*>(XH + rbase + q * 8);
            uint4 lb = *reinterpret_cast<const uint4*>(XL + rbase + q * 8);
            float rh[8], rl[8];
            unpack_bf16x8(hb, rh);
            unpack_bf16x8(lb, rl);
#pragma unroll
            for (int jj = 0; jj < 8; ++jj) {
                int col = cc * 32 + q * 8 + jj;
                float val = vals[row * 289 + col] + rh[jj] + rl[jj];
                v[q * 8 + jj] = val;
                ps += val;
                pq = fmaf(val, val, pq);
            }
        }
        part[cc][row][0] = ps;
        part[cc][row][1] = pq;
    }
    __syncthreads();
    float s1 = 0.f, s2 = 0.f;
#pragma unroll
    for (int k = 0; k < 8; ++k) { s1 += part[k][row][0]; s2 += part[k][row][1]; }
    float m = s1 * (1.f / 256.f);
    float var = s2 * (1.f / 256.f) - m * m;
    float rstd = rsqrtf(var + 1e-5f);
#pragma unroll
    for (int q = 0; q < 4; ++q) {
        int col0 = cc * 32 + q * 8;
        float4 g0 = *reinterpret_cast<const float4*>(G + col0);
        float4 g1 = *reinterpret_cast<const float4*>(G + col0 + 4);
        float4 b0 = *reinterpret_cast<const float4*>(BB + col0);
        float4 b1 = *reinterpret_cast<const float4*>(BB + col0 + 4);
        float gg[8] = {g0.x, g0.y, g0.z, g0.w, g1.x, g1.y, g1.z, g1.w};
        float bb2[8] = {b0.x, b0.y, b0.z, b0.w, b1.x, b1.y, b1.z, b1.w};
        unsigned hw[4], lw[4];
#pragma unroll
        for (int p2 = 0; p2 < 4; ++p2) {
            float y0 = (v[q * 8 + p2 * 2] - m) * rstd * gg[p2 * 2] + bb2[p2 * 2];
            float y1 = (v[q * 8 + p2 * 2 + 1] - m) * rstd * gg[p2 * 2 + 1] + bb2[p2 * 2 + 1];
            unsigned short h0 = bf16_rn(y0), h1 = bf16_rn(y1);
            unsigned short lo0 = bf16_rn(y0 - bf16f(h0)), lo1 = bf16_rn(y1 - bf16f(h1));
            hw[p2] = (unsigned)h0 | ((unsigned)h1 << 16);
            lw[p2] = (unsigned)lo0 | ((unsigned)lo1 << 16);
        }
        *reinterpret_cast<uint4*>(XH + rbase + q * 8) = make_uint4(hw[0], hw[1], hw[2], hw[3]);
        *reinterpret_cast<uint4*>(XL + rbase + q * 8) = make_uint4(lw[0], lw[1], lw[2], lw[3]);
    }
}

// ---------------------------------------------------------------------------
// K4: mean over tokens + classifier head (reads planes). grid 480, block 256.
__global__ __launch_bounds__(256) void cls_kernel(const unsigned short* __restrict__ XH,
                                                  const unsigned short* __restrict__ XL,
                                                  const float* __restrict__ W1,
                                                  const float* __restrict__ B1,
                                                  const float* __restrict__ W2,
                                                  const float* __restrict__ B2,
                                                  float* __restrict__ OUT) {
    int b = blockIdx.x;
    __shared__ float xm[256];
    __shared__ float hred[128];
    int tid = threadIdx.x;
    float sm = 0.f;
    for (int n = 0; n < SEQN; ++n) {
        size_t idx = ((size_t)b * SEQN + n) * CDIM + tid;
        sm += bf16f(XH[idx]) + bf16f(XL[idx]);
    }
    xm[tid] = sm * (1.f / 128.f);
    __syncthreads();
    if (tid < 128) {
        float a = B1[tid];
        for (int k = 0; k < CDIM; ++k) a = fmaf(xm[k], W1[k * 128 + tid], a);
        a = fmaxf(a, 0.f);
        hred[tid] = a * W2[tid];
    }
    __syncthreads();
    for (int off = 64; off > 0; off >>= 1) {
        if (tid < off) hred[tid] += hred[tid + off];
        __syncthreads();
    }
    if (tid == 0) OUT[b] = hred[0] + B2[0];
}

// ---------------------------------------------------------------------------
extern "C" void kernel_launch(void* const* d_in, const int* in_sizes, int n_in,
                              void* d_out, int out_size, void* d_ws, size_t ws_size,
                              hipStream_t stream) {
    const float* RW  = (const float*)d_in[0];
    const float* POS = (const float*)d_in[1];
    const float* CW1 = (const float*)d_in[2];
    const float* CB1 = (const float*)d_in[3];
    const float* CW2 = (const float*)d_in[4];
    const float* CB2 = (const float*)d_in[5];

    const size_t NTOK = (size_t)NSEQ * SEQN * CDIM;  // 15.7M
    unsigned short* OH = (unsigned short*)d_ws;
    unsigned short* OL = OH + NTOK;
    unsigned short* XH = OL + NTOK;
    unsigned short* XL = XH + NTOK;
    unsigned short* WtHi = XL + NTOK;
    unsigned short* WtLo = WtHi + (size_t)768 * 256;
    unsigned short* W2H = WtLo + (size_t)768 * 256;
    unsigned short* W2L = W2H + (size_t)256 * 256;

    prep_kernel<<<dim3(NSEQ, 4, 8), 256, 0, stream>>>(RW, POS, XH, XL);

    for (int li = 0; li < 2; ++li) {
        const float* qw = (const float*)d_in[6 + 6 * li];
        const float* qb = (const float*)d_in[7 + 6 * li];
        const float* pw = (const float*)d_in[8 + 6 * li];
        const float* pb = (const float*)d_in[9 + 6 * li];
        const float* lg = (const float*)d_in[10 + 6 * li];
        const float* lb = (const float*)d_in[11 + 6 * li];
        wsplit2_kernel<<<dim3(8, 32), 256, 0, stream>>>(qw, pw, WtHi, WtLo, W2H, W2L);
        attn_kernel<<<NSEQ * NH * 2, 256, 0, stream>>>(XH, XL, OH, OL, WtHi, WtLo, qb);
        projln_kernel<<<dim3(NSEQ, 4), 256, 0, stream>>>(OH, OL, XH, XL, W2H, W2L, pb, lg, lb);
    }

    cls_kernel<<<NSEQ, 256, 0, stream>>>(XH, XL, CW1, CB1, CW2, CB2, (float*)d_out);
}

// Round 9
// 784.666 us; speedup vs baseline: 1.5397x; 1.5397x over previous
//
#include <hip/hip_runtime.h>
#include <hip/hip_bf16.h>
#include <cmath>

#define NSEQ 480
#define SEQN 128
#define CDIM 256
#define NH 8
#define HD 32
#define TOPM 20

typedef float f32x4 __attribute__((ext_vector_type(4)));
typedef short bf16x8 __attribute__((ext_vector_type(8)));

__device__ __forceinline__ unsigned short bf16_rn(float x) {
    unsigned int u = __float_as_uint(x);
    unsigned int r = (u + 0x7FFFu + ((u >> 16) & 1u)) >> 16;
    return (unsigned short)r;
}
__device__ __forceinline__ float bf16f(unsigned short h) {
    return __uint_as_float(((unsigned int)h) << 16);
}
__device__ __forceinline__ unsigned int okey(float v) {
    unsigned int u = __float_as_uint(v);
    return (u >> 31) ? ~u : (u | 0x80000000u);
}
__device__ __forceinline__ float okey_inv(unsigned int k) {
    return __uint_as_float((k >> 31) ? (k & 0x7FFFFFFFu) : ~k);
}
__device__ __forceinline__ unsigned pk_bf16(float a, float b) {
    union { __hip_bfloat162 h; unsigned u; } cv;
    cv.h = __float22bfloat162_rn(make_float2(a, b));
    return cv.u;
}
__device__ __forceinline__ void unpack_bf16x8(uint4 u, float* o) {
    o[0] = bf16f((unsigned short)(u.x & 0xffffu)); o[1] = bf16f((unsigned short)(u.x >> 16));
    o[2] = bf16f((unsigned short)(u.y & 0xffffu)); o[3] = bf16f((unsigned short)(u.y >> 16));
    o[4] = bf16f((unsigned short)(u.z & 0xffffu)); o[5] = bf16f((unsigned short)(u.z >> 16));
    o[6] = bf16f((unsigned short)(u.w & 0xffffu)); o[7] = bf16f((unsigned short)(u.w >> 16));
}

// ---------------------------------------------------------------------------
// K1: transpose (B, C, N) -> (B, N, C), add pos_embed, emit split-bf16 planes.
// Packed pair stores: every plane store is a coalesced 4B word.
// grid (480, 4, 8), block 256.
__global__ __launch_bounds__(256) void prep_kernel(const float* __restrict__ RW,
                                                   const float* __restrict__ POS,
                                                   unsigned short* __restrict__ XH,
                                                   unsigned short* __restrict__ XL) {
    int b = blockIdx.x, n0 = blockIdx.y * 32, c0 = blockIdx.z * 32;
    __shared__ float tile[32][33];
    int tx = threadIdx.x & 31, ty = threadIdx.x >> 5;
#pragma unroll
    for (int jj = 0; jj < 4; ++jj) {
        int c = c0 + ty + 8 * jj;
        tile[ty + 8 * jj][tx] = RW[((size_t)b * CDIM + c) * SEQN + n0 + tx];
    }
    __syncthreads();
    // write: 32 n-rows x 16 col-pairs; 2 passes of 256 threads
    const int cp = threadIdx.x & 15;           // col pair 0..15
    const int nr = threadIdx.x >> 4;           // 0..15
#pragma unroll
    for (int pass = 0; pass < 2; ++pass) {
        int n = n0 + nr + 16 * pass;
        int c = c0 + cp * 2;
        const float* prow = POS + (n - n0 + n0) * CDIM + c;  // POS[n][c]
        float v0 = tile[cp * 2 + 0][nr + 16 * pass] + prow[0];
        float v1 = tile[cp * 2 + 1][nr + 16 * pass] + prow[1];
        unsigned short h0 = bf16_rn(v0), h1 = bf16_rn(v1);
        unsigned short l0 = bf16_rn(v0 - bf16f(h0)), l1 = bf16_rn(v1 - bf16f(h1));
        size_t widx = ((size_t)b * SEQN * CDIM + (size_t)n * CDIM + c) >> 1;
        reinterpret_cast<unsigned*>(XH)[widx] = (unsigned)h0 | ((unsigned)h1 << 16);
        reinterpret_cast<unsigned*>(XL)[widx] = (unsigned)l0 | ((unsigned)l1 << 16);
    }
}

// ---------------------------------------------------------------------------
// K1b: both weight splits for one layer in one launch.
// grid (8, 32): y<24 -> qkv W (256x768), y>=24 -> proj W (256x256).
__global__ __launch_bounds__(256) void wsplit2_kernel(
    const float* __restrict__ Wq, const float* __restrict__ Wp,
    unsigned short* __restrict__ QH, unsigned short* __restrict__ QL,
    unsigned short* __restrict__ PH, unsigned short* __restrict__ PL) {
    int k0 = blockIdx.x * 32;
    int yy = blockIdx.y;
    const float* W;
    unsigned short *WH, *WL;
    int ncols, j0;
    if (yy < 24) { W = Wq; WH = QH; WL = QL; ncols = 768; j0 = yy * 32; }
    else         { W = Wp; WH = PH; WL = PL; ncols = 256; j0 = (yy - 24) * 32; }
    __shared__ float tile[32][33];
    int tx = threadIdx.x & 31, ty = threadIdx.x >> 5;
#pragma unroll
    for (int jj = 0; jj < 4; ++jj)
        tile[ty + 8 * jj][tx] = W[(size_t)(k0 + ty + 8 * jj) * ncols + j0 + tx];
    __syncthreads();
#pragma unroll
    for (int jj = 0; jj < 4; ++jj) {
        float v = tile[tx][ty + 8 * jj];
        unsigned short hi = bf16_rn(v);
        unsigned short lo = bf16_rn(v - bf16f(hi));
        size_t idx = (size_t)(j0 + ty + 8 * jj) * 256 + k0 + tx;
        WH[idx] = hi;
        WL[idx] = lo;
    }
}

// ---------------------------------------------------------------------------
// K2: fused qkv + exact top-20 attention (round-5 structure: best measured).
// 256 threads / 4 waves, each wave owns 32 q-rows with TWO interleaved
// selection brackets per thread (ILP for the serial chain).
// Q/K split-bf16 (3-term MFMA), V and P single-bf16.
// grid 3840, bid = (b&7) + 8h + 64(b>>3).  LDS = 40 KiB -> 4 blocks/CU.
__global__ __launch_bounds__(256, 4) void attn_kernel(
    const unsigned short* __restrict__ XHi, const unsigned short* __restrict__ XLo,
    unsigned short* __restrict__ OH, unsigned short* __restrict__ OL,
    const unsigned short* __restrict__ WtHi, const unsigned short* __restrict__ WtLo,
    const float* __restrict__ BIAS) {
    const int bid = blockIdx.x;
    const int h = (bid >> 3) & 7;
    const int b = ((bid >> 6) << 3) | (bid & 7);
    const float scale = 0.17677669529663687f;  // 1/sqrt(32)

    // q/k: row-major [128][32], col swizzle d' = d ^ (((tok>>1)&3)<<3)
    // vT : [32][128],  col swizzle t' = t ^ ((d&7)<<3)
    __shared__ unsigned short qh[SEQN * HD], ql[SEQN * HD];
    __shared__ unsigned short kh[SEQN * HD], kl[SEQN * HD];
    __shared__ unsigned short vh[HD * SEQN];

    const int tid = threadIdx.x;
    const int w = tid >> 6;    // wave 0..3 -> token rows [w*32, w*32+32)
    const int l = tid & 63;
    const int l15 = l & 15;
    const int sct = l >> 4;
    const size_t xbase = (size_t)b * SEQN * CDIM;

    // ================= Phase 1: QKV via MFMA =================
    f32x4 acc[2][6];  // ni 0,1=q  2,3=k  4,5=v
#pragma unroll
    for (int mi = 0; mi < 2; ++mi)
#pragma unroll
        for (int ni = 0; ni < 6; ++ni) acc[mi][ni] = (f32x4){0.f, 0.f, 0.f, 0.f};

#pragma unroll 2
    for (int ks = 0; ks < 8; ++ks) {
        const int kb = ks * 32;
        bf16x8 ahi[2], alo[2];
#pragma unroll
        for (int mi = 0; mi < 2; ++mi) {
            int row = w * 32 + mi * 16 + l15;
            size_t off = xbase + row * CDIM + kb + sct * 8;
            ahi[mi] = *reinterpret_cast<const bf16x8*>(XHi + off);
            alo[mi] = *reinterpret_cast<const bf16x8*>(XLo + off);
        }
#pragma unroll
        for (int ni = 0; ni < 6; ++ni) {
            int j = ((ni >> 1) << 8) + h * HD + ((ni & 1) << 4) + l15;
            const int woff = j * 256 + kb + sct * 8;
            bf16x8 bh = *reinterpret_cast<const bf16x8*>(WtHi + woff);
            if (ni < 4) {
                bf16x8 bl = *reinterpret_cast<const bf16x8*>(WtLo + woff);
#pragma unroll
                for (int mi = 0; mi < 2; ++mi) {
                    acc[mi][ni] = __builtin_amdgcn_mfma_f32_16x16x32_bf16(ahi[mi], bh, acc[mi][ni], 0, 0, 0);
                    acc[mi][ni] = __builtin_amdgcn_mfma_f32_16x16x32_bf16(ahi[mi], bl, acc[mi][ni], 0, 0, 0);
                    acc[mi][ni] = __builtin_amdgcn_mfma_f32_16x16x32_bf16(alo[mi], bh, acc[mi][ni], 0, 0, 0);
                }
            } else {  // v: bf16 precision is enough
#pragma unroll
                for (int mi = 0; mi < 2; ++mi)
                    acc[mi][ni] = __builtin_amdgcn_mfma_f32_16x16x32_bf16(ahi[mi], bh, acc[mi][ni], 0, 0, 0);
            }
        }
    }
    // epilogue: bias (+scale for q), split q/k, bf16 v
#pragma unroll
    for (int ni = 0; ni < 6; ++ni) {
        const int sel = ni >> 1;
        const int dcol = ((ni & 1) << 4) + l15;
        const float bias = BIAS[(sel << 8) + h * HD + dcol];
#pragma unroll
        for (int mi = 0; mi < 2; ++mi) {
            const int tb = w * 32 + mi * 16 + sct * 4;
            if (sel == 2) {
                float v0 = acc[mi][ni][0] + bias, v1 = acc[mi][ni][1] + bias;
                float v2 = acc[mi][ni][2] + bias, v3 = acc[mi][ni][3] + bias;
                unsigned pA = pk_bf16(v0, v1), pB = pk_bf16(v2, v3);
                int c0i = tb ^ ((dcol & 7) << 3);
                *reinterpret_cast<uint2*>(&vh[dcol * SEQN + c0i]) = make_uint2(pA, pB);
            } else {
                unsigned short* ph = sel ? kh : qh;
                unsigned short* pl = sel ? kl : ql;
#pragma unroll
                for (int r = 0; r < 4; ++r) {
                    float v = acc[mi][ni][r] + bias;
                    if (sel == 0) v *= scale;
                    unsigned short hi = bf16_rn(v);
                    int token = tb + r;
                    int idx = token * HD + (dcol ^ (((token >> 1) & 3) << 3));
                    ph[idx] = hi;
                    pl[idx] = bf16_rn(v - bf16f(hi));
                }
            }
        }
    }
    __syncthreads();

    // ================= Phase 2: S^T = K·Q^T, in-register softmax ============
    f32x4 sacc[8][2];
#pragma unroll
    for (int mi = 0; mi < 8; ++mi)
#pragma unroll
        for (int ni = 0; ni < 2; ++ni) sacc[mi][ni] = (f32x4){0.f, 0.f, 0.f, 0.f};

    bf16x8 qfh[2], qfl[2];
#pragma unroll
    for (int ni = 0; ni < 2; ++ni) {
        int qrow = w * 32 + (ni << 4) + l15;
        int off = qrow * HD + ((sct * 8) ^ (((qrow >> 1) & 3) << 3));
        qfh[ni] = *reinterpret_cast<const bf16x8*>(qh + off);
        qfl[ni] = *reinterpret_cast<const bf16x8*>(ql + off);
    }
    __builtin_amdgcn_s_setprio(1);
#pragma unroll
    for (int mi = 0; mi < 8; ++mi) {
        int krow = (mi << 4) + l15;
        int off = krow * HD + ((sct * 8) ^ (((krow >> 1) & 3) << 3));
        bf16x8 kfh = *reinterpret_cast<const bf16x8*>(kh + off);
        bf16x8 kfl = *reinterpret_cast<const bf16x8*>(kl + off);
#pragma unroll
        for (int ni = 0; ni < 2; ++ni) {
            sacc[mi][ni] = __builtin_amdgcn_mfma_f32_16x16x32_bf16(kfh, qfh[ni], sacc[mi][ni], 0, 0, 0);
            sacc[mi][ni] = __builtin_amdgcn_mfma_f32_16x16x32_bf16(kfh, qfl[ni], sacc[mi][ni], 0, 0, 0);
            sacc[mi][ni] = __builtin_amdgcn_mfma_f32_16x16x32_bf16(kfl, qfh[ni], sacc[mi][ni], 0, 0, 0);
        }
    }
    __builtin_amdgcn_s_setprio(0);
    // ordered keys in place
#pragma unroll
    for (int mi = 0; mi < 8; ++mi)
#pragma unroll
        for (int ni = 0; ni < 2; ++ni)
#pragma unroll
            for (int r = 0; r < 4; ++r)
                sacc[mi][ni][r] = __uint_as_float(okey(sacc[mi][ni][r]));

    // row max and min (monotone in key domain)
    unsigned int km0 = 0u, km1 = 0u, kn0 = 0xFFFFFFFFu, kn1 = 0xFFFFFFFFu;
#pragma unroll
    for (int mi = 0; mi < 8; ++mi)
#pragma unroll
        for (int r = 0; r < 4; ++r) {
            unsigned int u0 = __float_as_uint(sacc[mi][0][r]);
            unsigned int u1 = __float_as_uint(sacc[mi][1][r]);
            km0 = max(km0, u0); kn0 = min(kn0, u0);
            km1 = max(km1, u1); kn1 = min(kn1, u1);
        }
    km0 = max(km0, (unsigned int)__shfl_xor((int)km0, 16));
    km0 = max(km0, (unsigned int)__shfl_xor((int)km0, 32));
    km1 = max(km1, (unsigned int)__shfl_xor((int)km1, 16));
    km1 = max(km1, (unsigned int)__shfl_xor((int)km1, 32));
    kn0 = min(kn0, (unsigned int)__shfl_xor((int)kn0, 16));
    kn0 = min(kn0, (unsigned int)__shfl_xor((int)kn0, 32));
    kn1 = min(kn1, (unsigned int)__shfl_xor((int)kn1, 16));
    kn1 = min(kn1, (unsigned int)__shfl_xor((int)kn1, 32));
    float mx0 = okey_inv(km0), mx1 = okey_inv(km1);

    // exact top-20 threshold per q-row: bracketed bisection over [kn, km+1],
    // two interleaved brackets (ILP), early exit at c==20
    unsigned p0, p1;
    {
        unsigned lo0 = kn0, hi0 = km0 + 1u, lo1 = kn1, hi1 = km1 + 1u;
        unsigned th0 = km0, th1 = km1;
        int dn0 = 0, dn1 = 0;
#pragma unroll 1
        for (int it = 0; it < 34; ++it) {
            if (__all(dn0 & dn1)) break;
            unsigned mid0 = lo0 + ((hi0 - lo0) >> 1);
            unsigned mid1 = lo1 + ((hi1 - lo1) >> 1);
            int c0 = 0, c1 = 0;
#pragma unroll
            for (int mi = 0; mi < 8; ++mi)
#pragma unroll
                for (int r = 0; r < 4; ++r) {
                    c0 += (__float_as_uint(sacc[mi][0][r]) >= mid0) ? 1 : 0;
                    c1 += (__float_as_uint(sacc[mi][1][r]) >= mid1) ? 1 : 0;
                }
            int mpk = c0 | (c1 << 8);
            mpk += __shfl_xor(mpk, 16);
            mpk += __shfl_xor(mpk, 32);
            c0 = mpk & 255;
            c1 = mpk >> 8;
            if (!dn0) {
                if (c0 == TOPM) { th0 = mid0; dn0 = 1; }
                else if (hi0 - lo0 <= 1u) { th0 = lo0; dn0 = 1; }
                else if (c0 > TOPM) lo0 = mid0;
                else hi0 = mid0;
            }
            if (!dn1) {
                if (c1 == TOPM) { th1 = mid1; dn1 = 1; }
                else if (hi1 - lo1 <= 1u) { th1 = lo1; dn1 = 1; }
                else if (c1 > TOPM) lo1 = mid1;
                else hi1 = mid1;
            }
        }
        p0 = th0; p1 = th1;
    }

    // masked exp (unnormalized) + row sums
    float s0 = 0.f, s1 = 0.f;
#pragma unroll
    for (int mi = 0; mi < 8; ++mi)
#pragma unroll
        for (int r = 0; r < 4; ++r) {
            unsigned int u0 = __float_as_uint(sacc[mi][0][r]);
            unsigned int u1 = __float_as_uint(sacc[mi][1][r]);
            float e0 = (u0 >= p0) ? __expf(okey_inv(u0) - mx0) : 0.f;
            float e1 = (u1 >= p1) ? __expf(okey_inv(u1) - mx1) : 0.f;
            sacc[mi][0][r] = e0;
            sacc[mi][1][r] = e1;
            s0 += e0;
            s1 += e1;
        }
    s0 += __shfl_xor(s0, 16);
    s0 += __shfl_xor(s0, 32);
    s1 += __shfl_xor(s1, 16);
    s1 += __shfl_xor(s1, 32);
    float i0 = 1.f / s0, i1 = 1.f / s1;

    unsigned w16[8][2][2];
#pragma unroll
    for (int mi = 0; mi < 8; ++mi)
#pragma unroll
        for (int ni = 0; ni < 2; ++ni)
#pragma unroll
            for (int p = 0; p < 2; ++p)
                w16[mi][ni][p] = pk_bf16(sacc[mi][ni][2 * p], sacc[mi][ni][2 * p + 1]);

    // ================= Phase 3: O = P·V via MFMA ==============
    f32x4 oacc[2][2];
#pragma unroll
    for (int mi = 0; mi < 2; ++mi)
#pragma unroll
        for (int ni = 0; ni < 2; ++ni) oacc[mi][ni] = (f32x4){0.f, 0.f, 0.f, 0.f};

#pragma unroll
    for (int k = 0; k < 4; ++k) {
        bf16x8 bvh[2];
#pragma unroll
        for (int nio = 0; nio < 2; ++nio) {
            int drow = (nio << 4) + l15;
            int off = drow * SEQN + ((k * 32 + sct * 8) ^ ((drow & 7) << 3));
            bvh[nio] = *reinterpret_cast<const bf16x8*>(vh + off);
        }
#pragma unroll
        for (int mio = 0; mio < 2; ++mio) {
            union { unsigned u[4]; bf16x8 v8; } aw;
#pragma unroll
            for (int j = 0; j < 4; ++j) {
                int src = l15 + ((sct & 1) << 5) + ((j >> 1) << 4);
                unsigned a0 = (unsigned)__shfl((int)w16[2 * k][mio][j & 1], src);
                unsigned a1 = (unsigned)__shfl((int)w16[2 * k + 1][mio][j & 1], src);
                aw.u[j] = (sct >= 2) ? a1 : a0;
            }
            __builtin_amdgcn_s_setprio(1);
#pragma unroll
            for (int nio = 0; nio < 2; ++nio)
                oacc[mio][nio] = __builtin_amdgcn_mfma_f32_16x16x32_bf16(aw.v8, bvh[nio], oacc[mio][nio], 0, 0, 0);
            __builtin_amdgcn_s_setprio(0);
        }
    }
    float invO[2][4];
#pragma unroll
    for (int mio = 0; mio < 2; ++mio)
#pragma unroll
        for (int r = 0; r < 4; ++r)
            invO[mio][r] = __shfl(mio ? i1 : i0, sct * 4 + r);
#pragma unroll
    for (int mio = 0; mio < 2; ++mio)
#pragma unroll
        for (int nio = 0; nio < 2; ++nio)
#pragma unroll
            for (int r = 0; r < 4; ++r) {
                int token = w * 32 + mio * 16 + sct * 4 + r;
                int d = (nio << 4) + l15;
                size_t idx = ((size_t)b * SEQN + token) * CDIM + h * HD + d;
                float v = oacc[mio][nio][r] * invO[mio][r];
                unsigned short hi = bf16_rn(v);
                OH[idx] = hi;
                OL[idx] = bf16_rn(v - bf16f(hi));
            }
}

// ---------------------------------------------------------------------------
// K3: MFMA proj GEMM + bias + residual + LayerNorm, 32 tokens per block.
// grid (480, 4), block 256 (4 waves, each 32 tok x 64 cols).  LDS ~39 KB.
__global__ __launch_bounds__(256, 4) void projln_kernel(
    const unsigned short* __restrict__ OHp, const unsigned short* __restrict__ OLp,
    unsigned short* __restrict__ XH, unsigned short* __restrict__ XL,
    const unsigned short* __restrict__ W2H, const unsigned short* __restrict__ W2L,
    const float* __restrict__ PB, const float* __restrict__ G,
    const float* __restrict__ BB) {
    const int b = blockIdx.x;
    const int t0 = blockIdx.y * 32;
    __shared__ float vals[32 * 289];
    __shared__ float part[8][32][2];

    const int tid = threadIdx.x;
    const int w = tid >> 6;
    const int l = tid & 63;
    const int l15 = l & 15;
    const int sct = l >> 4;

    f32x4 acc[2][4];
#pragma unroll
    for (int mi = 0; mi < 2; ++mi)
#pragma unroll
        for (int ni = 0; ni < 4; ++ni) acc[mi][ni] = (f32x4){0.f, 0.f, 0.f, 0.f};

    const size_t obase = ((size_t)b * SEQN + t0) * CDIM;
#pragma unroll 2
    for (int ks = 0; ks < 8; ++ks) {
        const int kb = ks * 32;
        bf16x8 ahi[2], alo[2];
#pragma unroll
        for (int mi = 0; mi < 2; ++mi) {
            size_t off = obase + (size_t)(mi * 16 + l15) * CDIM + kb + sct * 8;
            ahi[mi] = *reinterpret_cast<const bf16x8*>(OHp + off);
            alo[mi] = *reinterpret_cast<const bf16x8*>(OLp + off);
        }
#pragma unroll
        for (int ni = 0; ni < 4; ++ni) {
            int j = w * 64 + ni * 16 + l15;
            int woff = j * 256 + kb + sct * 8;
            bf16x8 bh = *reinterpret_cast<const bf16x8*>(W2H + woff);
            bf16x8 bl = *reinterpret_cast<const bf16x8*>(W2L + woff);
#pragma unroll
            for (int mi = 0; mi < 2; ++mi) {
                acc[mi][ni] = __builtin_amdgcn_mfma_f32_16x16x32_bf16(ahi[mi], bh, acc[mi][ni], 0, 0, 0);
                acc[mi][ni] = __builtin_amdgcn_mfma_f32_16x16x32_bf16(ahi[mi], bl, acc[mi][ni], 0, 0, 0);
                acc[mi][ni] = __builtin_amdgcn_mfma_f32_16x16x32_bf16(alo[mi], bh, acc[mi][ni], 0, 0, 0);
            }
        }
    }
#pragma unroll
    for (int ni = 0; ni < 4; ++ni) {
        int j = w * 64 + ni * 16 + l15;
        float bias = PB[j];
#pragma unroll
        for (int mi = 0; mi < 2; ++mi)
#pragma unroll
            for (int r = 0; r < 4; ++r) {
                int tok = mi * 16 + sct * 4 + r;
                vals[tok * 289 + j] = acc[mi][ni][r] + bias;
            }
    }
    __syncthreads();

    const int row = tid & 31;
    const int cc = tid >> 5;
    const size_t rbase = ((size_t)b * SEQN + t0 + row) * CDIM + cc * 32;
    float v[32];
    {
        float ps = 0.f, pq = 0.f;
#pragma unroll
        for (int q = 0; q < 4; ++q) {
            uint4 hb = *reinterpret_cast<const uint4*>(XH + rbase + q * 8);
            uint4 lb = *reinterpret_cast<const uint4*>(XL + rbase + q * 8);
            float rh[8], rl[8];
            unpack_bf16x8(hb, rh);
            unpack_bf16x8(lb, rl);
#pragma unroll
            for (int jj = 0; jj < 8; ++jj) {
                int col = cc * 32 + q * 8 + jj;
                float val = vals[row * 289 + col] + rh[jj] + rl[jj];
                v[q * 8 + jj] = val;
                ps += val;
                pq = fmaf(val, val, pq);
            }
        }
        part[cc][row][0] = ps;
        part[cc][row][1] = pq;
    }
    __syncthreads();
    float s1 = 0.f, s2 = 0.f;
#pragma unroll
    for (int k = 0; k < 8; ++k) { s1 += part[k][row][0]; s2 += part[k][row][1]; }
    float m = s1 * (1.f / 256.f);
    float var = s2 * (1.f / 256.f) - m * m;
    float rstd = rsqrtf(var + 1e-5f);
#pragma unroll
    for (int q = 0; q < 4; ++q) {
        int col0 = cc * 32 + q * 8;
        float4 g0 = *reinterpret_cast<const float4*>(G + col0);
        float4 g1 = *reinterpret_cast<const float4*>(G + col0 + 4);
        float4 b0 = *reinterpret_cast<const float4*>(BB + col0);
        float4 b1 = *reinterpret_cast<const float4*>(BB + col0 + 4);
        float gg[8] = {g0.x, g0.y, g0.z, g0.w, g1.x, g1.y, g1.z, g1.w};
        float bb2[8] = {b0.x, b0.y, b0.z, b0.w, b1.x, b1.y, b1.z, b1.w};
        unsigned hw[4], lw[4];
#pragma unroll
        for (int p2 = 0; p2 < 4; ++p2) {
            float y0 = (v[q * 8 + p2 * 2] - m) * rstd * gg[p2 * 2] + bb2[p2 * 2];
            float y1 = (v[q * 8 + p2 * 2 + 1] - m) * rstd * gg[p2 * 2 + 1] + bb2[p2 * 2 + 1];
            unsigned short h0 = bf16_rn(y0), h1 = bf16_rn(y1);
            unsigned short lo0 = bf16_rn(y0 - bf16f(h0)), lo1 = bf16_rn(y1 - bf16f(h1));
            hw[p2] = (unsigned)h0 | ((unsigned)h1 << 16);
            lw[p2] = (unsigned)lo0 | ((unsigned)lo1 << 16);
        }
        *reinterpret_cast<uint4*>(XH + rbase + q * 8) = make_uint4(hw[0], hw[1], hw[2], hw[3]);
        *reinterpret_cast<uint4*>(XL + rbase + q * 8) = make_uint4(lw[0], lw[1], lw[2], lw[3]);
    }
}

// ---------------------------------------------------------------------------
// K4: mean over tokens + classifier head (reads planes). grid 480, block 256.
__global__ __launch_bounds__(256) void cls_kernel(const unsigned short* __restrict__ XH,
                                                  const unsigned short* __restrict__ XL,
                                                  const float* __restrict__ W1,
                                                  const float* __restrict__ B1,
                                                  const float* __restrict__ W2,
                                                  const float* __restrict__ B2,
                                                  float* __restrict__ OUT) {
    int b = blockIdx.x;
    __shared__ float xm[256];
    __shared__ float hred[128];
    int tid = threadIdx.x;
    float sm = 0.f;
    for (int n = 0; n < SEQN; ++n) {
        size_t idx = ((size_t)b * SEQN + n) * CDIM + tid;
        sm += bf16f(XH[idx]) + bf16f(XL[idx]);
    }
    xm[tid] = sm * (1.f / 128.f);
    __syncthreads();
    if (tid < 128) {
        float a = B1[tid];
        for (int k = 0; k < CDIM; ++k) a = fmaf(xm[k], W1[k * 128 + tid], a);
        a = fmaxf(a, 0.f);
        hred[tid] = a * W2[tid];
    }
    __syncthreads();
    for (int off = 64; off > 0; off >>= 1) {
        if (tid < off) hred[tid] += hred[tid + off];
        __syncthreads();
    }
    if (tid == 0) OUT[b] = hred[0] + B2[0];
}

// ---------------------------------------------------------------------------
extern "C" void kernel_launch(void* const* d_in, const int* in_sizes, int n_in,
                              void* d_out, int out_size, void* d_ws, size_t ws_size,
                              hipStream_t stream) {
    const float* RW  = (const float*)d_in[0];
    const float* POS = (const float*)d_in[1];
    const float* CW1 = (const float*)d_in[2];
    const float* CB1 = (const float*)d_in[3];
    const float* CW2 = (const float*)d_in[4];
    const float* CB2 = (const float*)d_in[5];

    const size_t NTOK = (size_t)NSEQ * SEQN * CDIM;  // 15.7M
    unsigned short* OH = (unsigned short*)d_ws;
    unsigned short* OL = OH + NTOK;
    unsigned short* XH = OL + NTOK;
    unsigned short* XL = XH + NTOK;
    unsigned short* WtHi = XL + NTOK;
    unsigned short* WtLo = WtHi + (size_t)768 * 256;
    unsigned short* W2H = WtLo + (size_t)768 * 256;
    unsigned short* W2L = W2H + (size_t)256 * 256;

    prep_kernel<<<dim3(NSEQ, 4, 8), 256, 0, stream>>>(RW, POS, XH, XL);

    for (int li = 0; li < 2; ++li) {
        const float* qw = (const float*)d_in[6 + 6 * li];
        const float* qb = (const float*)d_in[7 + 6 * li];
        const float* pw = (const float*)d_in[8 + 6 * li];
        const float* pb = (const float*)d_in[9 + 6 * li];
        const float* lg = (const float*)d_in[10 + 6 * li];
        const float* lb = (const float*)d_in[11 + 6 * li];
        wsplit2_kernel<<<dim3(8, 32), 256, 0, stream>>>(qw, pw, WtHi, WtLo, W2H, W2L);
        attn_kernel<<<NSEQ * NH, 256, 0, stream>>>(XH, XL, OH, OL, WtHi, WtLo, qb);
        projln_kernel<<<dim3(NSEQ, 4), 256, 0, stream>>>(OH, OL, XH, XL, W2H, W2L, pb, lg, lb);
    }

    cls_kernel<<<NSEQ, 256, 0, stream>>>(XH, XL, CW1, CB1, CW2, CB2, (float*)d_out);
}

// Round 10
// 746.556 us; speedup vs baseline: 1.6183x; 1.0510x over previous
//
#include <hip/hip_runtime.h>
#include <hip/hip_bf16.h>
#include <cmath>

#define NSEQ 480
#define SEQN 128
#define CDIM 256
#define NH 8
#define HD 32
#define TOPM 20

typedef float f32x4 __attribute__((ext_vector_type(4)));
typedef short bf16x8 __attribute__((ext_vector_type(8)));

__device__ __forceinline__ unsigned short bf16_rn(float x) {
    unsigned int u = __float_as_uint(x);
    unsigned int r = (u + 0x7FFFu + ((u >> 16) & 1u)) >> 16;
    return (unsigned short)r;
}
__device__ __forceinline__ float bf16f(unsigned short h) {
    return __uint_as_float(((unsigned int)h) << 16);
}
__device__ __forceinline__ unsigned int okey(float v) {
    unsigned int u = __float_as_uint(v);
    return (u >> 31) ? ~u : (u | 0x80000000u);
}
__device__ __forceinline__ float okey_inv(unsigned int k) {
    return __uint_as_float((k >> 31) ? (k & 0x7FFFFFFFu) : ~k);
}
__device__ __forceinline__ unsigned pk_bf16(float a, float b) {
    union { __hip_bfloat162 h; unsigned u; } cv;
    cv.h = __float22bfloat162_rn(make_float2(a, b));
    return cv.u;
}
__device__ __forceinline__ void unpack_bf16x8(uint4 u, float* o) {
    o[0] = bf16f((unsigned short)(u.x & 0xffffu)); o[1] = bf16f((unsigned short)(u.x >> 16));
    o[2] = bf16f((unsigned short)(u.y & 0xffffu)); o[3] = bf16f((unsigned short)(u.y >> 16));
    o[4] = bf16f((unsigned short)(u.z & 0xffffu)); o[5] = bf16f((unsigned short)(u.z >> 16));
    o[6] = bf16f((unsigned short)(u.w & 0xffffu)); o[7] = bf16f((unsigned short)(u.w >> 16));
}

// ---------------------------------------------------------------------------
// K1: transpose (B, C, N) -> (B, N, C), add pos_embed, emit split-bf16 planes.
// Packed pair stores: every plane store is a coalesced 4B word.
__global__ __launch_bounds__(256) void prep_kernel(const float* __restrict__ RW,
                                                   const float* __restrict__ POS,
                                                   unsigned short* __restrict__ XH,
                                                   unsigned short* __restrict__ XL) {
    int b = blockIdx.x, n0 = blockIdx.y * 32, c0 = blockIdx.z * 32;
    __shared__ float tile[32][33];
    int tx = threadIdx.x & 31, ty = threadIdx.x >> 5;
#pragma unroll
    for (int jj = 0; jj < 4; ++jj) {
        int c = c0 + ty + 8 * jj;
        tile[ty + 8 * jj][tx] = RW[((size_t)b * CDIM + c) * SEQN + n0 + tx];
    }
    __syncthreads();
    const int cp = threadIdx.x & 15;           // col pair 0..15
    const int nr = threadIdx.x >> 4;           // 0..15
#pragma unroll
    for (int pass = 0; pass < 2; ++pass) {
        int n = n0 + nr + 16 * pass;
        int c = c0 + cp * 2;
        const float* prow = POS + (size_t)n * CDIM + c;
        float v0 = tile[cp * 2 + 0][nr + 16 * pass] + prow[0];
        float v1 = tile[cp * 2 + 1][nr + 16 * pass] + prow[1];
        unsigned short h0 = bf16_rn(v0), h1 = bf16_rn(v1);
        unsigned short l0 = bf16_rn(v0 - bf16f(h0)), l1 = bf16_rn(v1 - bf16f(h1));
        size_t widx = ((size_t)b * SEQN * CDIM + (size_t)n * CDIM + c) >> 1;
        reinterpret_cast<unsigned*>(XH)[widx] = (unsigned)h0 | ((unsigned)h1 << 16);
        reinterpret_cast<unsigned*>(XL)[widx] = (unsigned)l0 | ((unsigned)l1 << 16);
    }
}

// ---------------------------------------------------------------------------
// K1b: ALL weight splits (both layers) in one launch.
// grid (8, 64): yy%32<24 -> qkv W (256x768), else proj W (256x256); yy/32 = layer.
__global__ __launch_bounds__(256) void wsplit_all_kernel(
    const float* __restrict__ Wq0, const float* __restrict__ Wp0,
    const float* __restrict__ Wq1, const float* __restrict__ Wp1,
    unsigned short* __restrict__ WBUF) {
    int k0 = blockIdx.x * 32;
    int yy = blockIdx.y;
    int li = yy >> 5;
    int ys = yy & 31;
    const size_t QN = (size_t)768 * 256, PN = (size_t)256 * 256;
    const size_t LSTRIDE = 2 * QN + 2 * PN;
    unsigned short* base = WBUF + li * LSTRIDE;
    const float* W;
    unsigned short *WH, *WL;
    int ncols, j0;
    if (ys < 24) {
        W = li ? Wq1 : Wq0; WH = base; WL = base + QN; ncols = 768; j0 = ys * 32;
    } else {
        W = li ? Wp1 : Wp0; WH = base + 2 * QN; WL = base + 2 * QN + PN; ncols = 256; j0 = (ys - 24) * 32;
    }
    __shared__ float tile[32][33];
    int tx = threadIdx.x & 31, ty = threadIdx.x >> 5;
#pragma unroll
    for (int jj = 0; jj < 4; ++jj)
        tile[ty + 8 * jj][tx] = W[(size_t)(k0 + ty + 8 * jj) * ncols + j0 + tx];
    __syncthreads();
#pragma unroll
    for (int jj = 0; jj < 4; ++jj) {
        float v = tile[tx][ty + 8 * jj];
        unsigned short hi = bf16_rn(v);
        unsigned short lo = bf16_rn(v - bf16f(hi));
        size_t idx = (size_t)(j0 + ty + 8 * jj) * 256 + k0 + tx;
        WH[idx] = hi;
        WL[idx] = lo;
    }
}

// ---------------------------------------------------------------------------
// K2: fused qkv + exact top-20 attention (round-5 structure: best measured).
// O written as SINGLE bf16 plane (error budget spend; halves O stores/traffic).
__global__ __launch_bounds__(256, 4) void attn_kernel(
    const unsigned short* __restrict__ XHi, const unsigned short* __restrict__ XLo,
    unsigned short* __restrict__ OH,
    const unsigned short* __restrict__ WtHi, const unsigned short* __restrict__ WtLo,
    const float* __restrict__ BIAS) {
    const int bid = blockIdx.x;
    const int h = (bid >> 3) & 7;
    const int b = ((bid >> 6) << 3) | (bid & 7);
    const float scale = 0.17677669529663687f;  // 1/sqrt(32)

    __shared__ unsigned short qh[SEQN * HD], ql[SEQN * HD];
    __shared__ unsigned short kh[SEQN * HD], kl[SEQN * HD];
    __shared__ unsigned short vh[HD * SEQN];

    const int tid = threadIdx.x;
    const int w = tid >> 6;
    const int l = tid & 63;
    const int l15 = l & 15;
    const int sct = l >> 4;
    const size_t xbase = (size_t)b * SEQN * CDIM;

    // ================= Phase 1: QKV via MFMA =================
    f32x4 acc[2][6];  // ni 0,1=q  2,3=k  4,5=v
#pragma unroll
    for (int mi = 0; mi < 2; ++mi)
#pragma unroll
        for (int ni = 0; ni < 6; ++ni) acc[mi][ni] = (f32x4){0.f, 0.f, 0.f, 0.f};

#pragma unroll 2
    for (int ks = 0; ks < 8; ++ks) {
        const int kb = ks * 32;
        bf16x8 ahi[2], alo[2];
#pragma unroll
        for (int mi = 0; mi < 2; ++mi) {
            int row = w * 32 + mi * 16 + l15;
            size_t off = xbase + row * CDIM + kb + sct * 8;
            ahi[mi] = *reinterpret_cast<const bf16x8*>(XHi + off);
            alo[mi] = *reinterpret_cast<const bf16x8*>(XLo + off);
        }
#pragma unroll
        for (int ni = 0; ni < 6; ++ni) {
            int j = ((ni >> 1) << 8) + h * HD + ((ni & 1) << 4) + l15;
            const int woff = j * 256 + kb + sct * 8;
            bf16x8 bh = *reinterpret_cast<const bf16x8*>(WtHi + woff);
            if (ni < 4) {
                bf16x8 bl = *reinterpret_cast<const bf16x8*>(WtLo + woff);
#pragma unroll
                for (int mi = 0; mi < 2; ++mi) {
                    acc[mi][ni] = __builtin_amdgcn_mfma_f32_16x16x32_bf16(ahi[mi], bh, acc[mi][ni], 0, 0, 0);
                    acc[mi][ni] = __builtin_amdgcn_mfma_f32_16x16x32_bf16(ahi[mi], bl, acc[mi][ni], 0, 0, 0);
                    acc[mi][ni] = __builtin_amdgcn_mfma_f32_16x16x32_bf16(alo[mi], bh, acc[mi][ni], 0, 0, 0);
                }
            } else {
#pragma unroll
                for (int mi = 0; mi < 2; ++mi)
                    acc[mi][ni] = __builtin_amdgcn_mfma_f32_16x16x32_bf16(ahi[mi], bh, acc[mi][ni], 0, 0, 0);
            }
        }
    }
#pragma unroll
    for (int ni = 0; ni < 6; ++ni) {
        const int sel = ni >> 1;
        const int dcol = ((ni & 1) << 4) + l15;
        const float bias = BIAS[(sel << 8) + h * HD + dcol];
#pragma unroll
        for (int mi = 0; mi < 2; ++mi) {
            const int tb = w * 32 + mi * 16 + sct * 4;
            if (sel == 2) {
                float v0 = acc[mi][ni][0] + bias, v1 = acc[mi][ni][1] + bias;
                float v2 = acc[mi][ni][2] + bias, v3 = acc[mi][ni][3] + bias;
                unsigned pA = pk_bf16(v0, v1), pB = pk_bf16(v2, v3);
                int c0i = tb ^ ((dcol & 7) << 3);
                *reinterpret_cast<uint2*>(&vh[dcol * SEQN + c0i]) = make_uint2(pA, pB);
            } else {
                unsigned short* ph = sel ? kh : qh;
                unsigned short* pl = sel ? kl : ql;
#pragma unroll
                for (int r = 0; r < 4; ++r) {
                    float v = acc[mi][ni][r] + bias;
                    if (sel == 0) v *= scale;
                    unsigned short hi = bf16_rn(v);
                    int token = tb + r;
                    int idx = token * HD + (dcol ^ (((token >> 1) & 3) << 3));
                    ph[idx] = hi;
                    pl[idx] = bf16_rn(v - bf16f(hi));
                }
            }
        }
    }
    __syncthreads();

    // ================= Phase 2: S^T = K·Q^T, in-register softmax ============
    f32x4 sacc[8][2];
#pragma unroll
    for (int mi = 0; mi < 8; ++mi)
#pragma unroll
        for (int ni = 0; ni < 2; ++ni) sacc[mi][ni] = (f32x4){0.f, 0.f, 0.f, 0.f};

    bf16x8 qfh[2], qfl[2];
#pragma unroll
    for (int ni = 0; ni < 2; ++ni) {
        int qrow = w * 32 + (ni << 4) + l15;
        int off = qrow * HD + ((sct * 8) ^ (((qrow >> 1) & 3) << 3));
        qfh[ni] = *reinterpret_cast<const bf16x8*>(qh + off);
        qfl[ni] = *reinterpret_cast<const bf16x8*>(ql + off);
    }
    __builtin_amdgcn_s_setprio(1);
#pragma unroll
    for (int mi = 0; mi < 8; ++mi) {
        int krow = (mi << 4) + l15;
        int off = krow * HD + ((sct * 8) ^ (((krow >> 1) & 3) << 3));
        bf16x8 kfh = *reinterpret_cast<const bf16x8*>(kh + off);
        bf16x8 kfl = *reinterpret_cast<const bf16x8*>(kl + off);
#pragma unroll
        for (int ni = 0; ni < 2; ++ni) {
            sacc[mi][ni] = __builtin_amdgcn_mfma_f32_16x16x32_bf16(kfh, qfh[ni], sacc[mi][ni], 0, 0, 0);
            sacc[mi][ni] = __builtin_amdgcn_mfma_f32_16x16x32_bf16(kfh, qfl[ni], sacc[mi][ni], 0, 0, 0);
            sacc[mi][ni] = __builtin_amdgcn_mfma_f32_16x16x32_bf16(kfl, qfh[ni], sacc[mi][ni], 0, 0, 0);
        }
    }
    __builtin_amdgcn_s_setprio(0);
#pragma unroll
    for (int mi = 0; mi < 8; ++mi)
#pragma unroll
        for (int ni = 0; ni < 2; ++ni)
#pragma unroll
            for (int r = 0; r < 4; ++r)
                sacc[mi][ni][r] = __uint_as_float(okey(sacc[mi][ni][r]));

    unsigned int km0 = 0u, km1 = 0u, kn0 = 0xFFFFFFFFu, kn1 = 0xFFFFFFFFu;
#pragma unroll
    for (int mi = 0; mi < 8; ++mi)
#pragma unroll
        for (int r = 0; r < 4; ++r) {
            unsigned int u0 = __float_as_uint(sacc[mi][0][r]);
            unsigned int u1 = __float_as_uint(sacc[mi][1][r]);
            km0 = max(km0, u0); kn0 = min(kn0, u0);
            km1 = max(km1, u1); kn1 = min(kn1, u1);
        }
    km0 = max(km0, (unsigned int)__shfl_xor((int)km0, 16));
    km0 = max(km0, (unsigned int)__shfl_xor((int)km0, 32));
    km1 = max(km1, (unsigned int)__shfl_xor((int)km1, 16));
    km1 = max(km1, (unsigned int)__shfl_xor((int)km1, 32));
    kn0 = min(kn0, (unsigned int)__shfl_xor((int)kn0, 16));
    kn0 = min(kn0, (unsigned int)__shfl_xor((int)kn0, 32));
    kn1 = min(kn1, (unsigned int)__shfl_xor((int)kn1, 16));
    kn1 = min(kn1, (unsigned int)__shfl_xor((int)kn1, 32));
    float mx0 = okey_inv(km0), mx1 = okey_inv(km1);

    unsigned p0, p1;
    {
        unsigned lo0 = kn0, hi0 = km0 + 1u, lo1 = kn1, hi1 = km1 + 1u;
        unsigned th0 = km0, th1 = km1;
        int dn0 = 0, dn1 = 0;
#pragma unroll 1
        for (int it = 0; it < 34; ++it) {
            if (__all(dn0 & dn1)) break;
            unsigned mid0 = lo0 + ((hi0 - lo0) >> 1);
            unsigned mid1 = lo1 + ((hi1 - lo1) >> 1);
            int c0 = 0, c1 = 0;
#pragma unroll
            for (int mi = 0; mi < 8; ++mi)
#pragma unroll
                for (int r = 0; r < 4; ++r) {
                    c0 += (__float_as_uint(sacc[mi][0][r]) >= mid0) ? 1 : 0;
                    c1 += (__float_as_uint(sacc[mi][1][r]) >= mid1) ? 1 : 0;
                }
            int mpk = c0 | (c1 << 8);
            mpk += __shfl_xor(mpk, 16);
            mpk += __shfl_xor(mpk, 32);
            c0 = mpk & 255;
            c1 = mpk >> 8;
            if (!dn0) {
                if (c0 == TOPM) { th0 = mid0; dn0 = 1; }
                else if (hi0 - lo0 <= 1u) { th0 = lo0; dn0 = 1; }
                else if (c0 > TOPM) lo0 = mid0;
                else hi0 = mid0;
            }
            if (!dn1) {
                if (c1 == TOPM) { th1 = mid1; dn1 = 1; }
                else if (hi1 - lo1 <= 1u) { th1 = lo1; dn1 = 1; }
                else if (c1 > TOPM) lo1 = mid1;
                else hi1 = mid1;
            }
        }
        p0 = th0; p1 = th1;
    }

    float s0 = 0.f, s1 = 0.f;
#pragma unroll
    for (int mi = 0; mi < 8; ++mi)
#pragma unroll
        for (int r = 0; r < 4; ++r) {
            unsigned int u0 = __float_as_uint(sacc[mi][0][r]);
            unsigned int u1 = __float_as_uint(sacc[mi][1][r]);
            float e0 = (u0 >= p0) ? __expf(okey_inv(u0) - mx0) : 0.f;
            float e1 = (u1 >= p1) ? __expf(okey_inv(u1) - mx1) : 0.f;
            sacc[mi][0][r] = e0;
            sacc[mi][1][r] = e1;
            s0 += e0;
            s1 += e1;
        }
    s0 += __shfl_xor(s0, 16);
    s0 += __shfl_xor(s0, 32);
    s1 += __shfl_xor(s1, 16);
    s1 += __shfl_xor(s1, 32);
    float i0 = 1.f / s0, i1 = 1.f / s1;

    unsigned w16[8][2][2];
#pragma unroll
    for (int mi = 0; mi < 8; ++mi)
#pragma unroll
        for (int ni = 0; ni < 2; ++ni)
#pragma unroll
            for (int p = 0; p < 2; ++p)
                w16[mi][ni][p] = pk_bf16(sacc[mi][ni][2 * p], sacc[mi][ni][2 * p + 1]);

    // ================= Phase 3: O = P·V via MFMA ==============
    f32x4 oacc[2][2];
#pragma unroll
    for (int mi = 0; mi < 2; ++mi)
#pragma unroll
        for (int ni = 0; ni < 2; ++ni) oacc[mi][ni] = (f32x4){0.f, 0.f, 0.f, 0.f};

#pragma unroll
    for (int k = 0; k < 4; ++k) {
        bf16x8 bvh[2];
#pragma unroll
        for (int nio = 0; nio < 2; ++nio) {
            int drow = (nio << 4) + l15;
            int off = drow * SEQN + ((k * 32 + sct * 8) ^ ((drow & 7) << 3));
            bvh[nio] = *reinterpret_cast<const bf16x8*>(vh + off);
        }
#pragma unroll
        for (int mio = 0; mio < 2; ++mio) {
            union { unsigned u[4]; bf16x8 v8; } aw;
#pragma unroll
            for (int j = 0; j < 4; ++j) {
                int src = l15 + ((sct & 1) << 5) + ((j >> 1) << 4);
                unsigned a0 = (unsigned)__shfl((int)w16[2 * k][mio][j & 1], src);
                unsigned a1 = (unsigned)__shfl((int)w16[2 * k + 1][mio][j & 1], src);
                aw.u[j] = (sct >= 2) ? a1 : a0;
            }
            __builtin_amdgcn_s_setprio(1);
#pragma unroll
            for (int nio = 0; nio < 2; ++nio)
                oacc[mio][nio] = __builtin_amdgcn_mfma_f32_16x16x32_bf16(aw.v8, bvh[nio], oacc[mio][nio], 0, 0, 0);
            __builtin_amdgcn_s_setprio(0);
        }
    }
    float invO[2][4];
#pragma unroll
    for (int mio = 0; mio < 2; ++mio)
#pragma unroll
        for (int r = 0; r < 4; ++r)
            invO[mio][r] = __shfl(mio ? i1 : i0, sct * 4 + r);
#pragma unroll
    for (int mio = 0; mio < 2; ++mio)
#pragma unroll
        for (int nio = 0; nio < 2; ++nio)
#pragma unroll
            for (int r = 0; r < 4; ++r) {
                int token = w * 32 + mio * 16 + sct * 4 + r;
                int d = (nio << 4) + l15;
                size_t idx = ((size_t)b * SEQN + token) * CDIM + h * HD + d;
                OH[idx] = bf16_rn(oacc[mio][nio][r] * invO[mio][r]);
            }
}

// ---------------------------------------------------------------------------
// K3: MFMA proj GEMM (A = single-bf16 O, B split -> 2-term) + bias + residual
// + LayerNorm, 32 tokens per block.  grid (480, 4), block 256.
__global__ __launch_bounds__(256, 4) void projln_kernel(
    const unsigned short* __restrict__ OHp,
    unsigned short* __restrict__ XH, unsigned short* __restrict__ XL,
    const unsigned short* __restrict__ W2H, const unsigned short* __restrict__ W2L,
    const float* __restrict__ PB, const float* __restrict__ G,
    const float* __restrict__ BB) {
    const int b = blockIdx.x;
    const int t0 = blockIdx.y * 32;
    __shared__ float vals[32 * 289];
    __shared__ float part[8][32][2];

    const int tid = threadIdx.x;
    const int w = tid >> 6;
    const int l = tid & 63;
    const int l15 = l & 15;
    const int sct = l >> 4;

    f32x4 acc[2][4];
#pragma unroll
    for (int mi = 0; mi < 2; ++mi)
#pragma unroll
        for (int ni = 0; ni < 4; ++ni) acc[mi][ni] = (f32x4){0.f, 0.f, 0.f, 0.f};

    const size_t obase = ((size_t)b * SEQN + t0) * CDIM;
#pragma unroll 2
    for (int ks = 0; ks < 8; ++ks) {
        const int kb = ks * 32;
        bf16x8 ahi[2];
#pragma unroll
        for (int mi = 0; mi < 2; ++mi) {
            size_t off = obase + (size_t)(mi * 16 + l15) * CDIM + kb + sct * 8;
            ahi[mi] = *reinterpret_cast<const bf16x8*>(OHp + off);
        }
#pragma unroll
        for (int ni = 0; ni < 4; ++ni) {
            int j = w * 64 + ni * 16 + l15;
            int woff = j * 256 + kb + sct * 8;
            bf16x8 bh = *reinterpret_cast<const bf16x8*>(W2H + woff);
            bf16x8 bl = *reinterpret_cast<const bf16x8*>(W2L + woff);
#pragma unroll
            for (int mi = 0; mi < 2; ++mi) {
                acc[mi][ni] = __builtin_amdgcn_mfma_f32_16x16x32_bf16(ahi[mi], bh, acc[mi][ni], 0, 0, 0);
                acc[mi][ni] = __builtin_amdgcn_mfma_f32_16x16x32_bf16(ahi[mi], bl, acc[mi][ni], 0, 0, 0);
            }
        }
    }
#pragma unroll
    for (int ni = 0; ni < 4; ++ni) {
        int j = w * 64 + ni * 16 + l15;
        float bias = PB[j];
#pragma unroll
        for (int mi = 0; mi < 2; ++mi)
#pragma unroll
            for (int r = 0; r < 4; ++r) {
                int tok = mi * 16 + sct * 4 + r;
                vals[tok * 289 + j] = acc[mi][ni][r] + bias;
            }
    }
    __syncthreads();

    const int row = tid & 31;
    const int cc = tid >> 5;
    const size_t rbase = ((size_t)b * SEQN + t0 + row) * CDIM + cc * 32;
    float v[32];
    {
        float ps = 0.f, pq = 0.f;
#pragma unroll
        for (int q = 0; q < 4; ++q) {
            uint4 hb = *reinterpret_cast<const uint4*>(XH + rbase + q * 8);
            uint4 lb = *reinterpret_cast<const uint4*>(XL + rbase + q * 8);
            float rh[8], rl[8];
            unpack_bf16x8(hb, rh);
            unpack_bf16x8(lb, rl);
#pragma unroll
            for (int jj = 0; jj < 8; ++jj) {
                int col = cc * 32 + q * 8 + jj;
                float val = vals[row * 289 + col] + rh[jj] + rl[jj];
                v[q * 8 + jj] = val;
                ps += val;
                pq = fmaf(val, val, pq);
            }
        }
        part[cc][row][0] = ps;
        part[cc][row][1] = pq;
    }
    __syncthreads();
    float s1 = 0.f, s2 = 0.f;
#pragma unroll
    for (int k = 0; k < 8; ++k) { s1 += part[k][row][0]; s2 += part[k][row][1]; }
    float m = s1 * (1.f / 256.f);
    float var = s2 * (1.f / 256.f) - m * m;
    float rstd = rsqrtf(var + 1e-5f);
#pragma unroll
    for (int q = 0; q < 4; ++q) {
        int col0 = cc * 32 + q * 8;
        float4 g0 = *reinterpret_cast<const float4*>(G + col0);
        float4 g1 = *reinterpret_cast<const float4*>(G + col0 + 4);
        float4 b0 = *reinterpret_cast<const float4*>(BB + col0);
        float4 b1 = *reinterpret_cast<const float4*>(BB + col0 + 4);
        float gg[8] = {g0.x, g0.y, g0.z, g0.w, g1.x, g1.y, g1.z, g1.w};
        float bb2[8] = {b0.x, b0.y, b0.z, b0.w, b1.x, b1.y, b1.z, b1.w};
        unsigned hw[4], lw[4];
#pragma unroll
        for (int p2 = 0; p2 < 4; ++p2) {
            float y0 = (v[q * 8 + p2 * 2] - m) * rstd * gg[p2 * 2] + bb2[p2 * 2];
            float y1 = (v[q * 8 + p2 * 2 + 1] - m) * rstd * gg[p2 * 2 + 1] + bb2[p2 * 2 + 1];
            unsigned short h0 = bf16_rn(y0), h1 = bf16_rn(y1);
            unsigned short lo0 = bf16_rn(y0 - bf16f(h0)), lo1 = bf16_rn(y1 - bf16f(h1));
            hw[p2] = (unsigned)h0 | ((unsigned)h1 << 16);
            lw[p2] = (unsigned)lo0 | ((unsigned)lo1 << 16);
        }
        *reinterpret_cast<uint4*>(XH + rbase + q * 8) = make_uint4(hw[0], hw[1], hw[2], hw[3]);
        *reinterpret_cast<uint4*>(XL + rbase + q * 8) = make_uint4(lw[0], lw[1], lw[2], lw[3]);
    }
}

// ---------------------------------------------------------------------------
// K4: mean over tokens + classifier head (reads planes). grid 480, block 256.
__global__ __launch_bounds__(256) void cls_kernel(const unsigned short* __restrict__ XH,
                                                  const unsigned short* __restrict__ XL,
                                                  const float* __restrict__ W1,
                                                  const float* __restrict__ B1,
                                                  const float* __restrict__ W2,
                                                  const float* __restrict__ B2,
                                                  float* __restrict__ OUT) {
    int b = blockIdx.x;
    __shared__ float xm[256];
    __shared__ float hred[128];
    int tid = threadIdx.x;
    float sm = 0.f;
    for (int n = 0; n < SEQN; ++n) {
        size_t idx = ((size_t)b * SEQN + n) * CDIM + tid;
        sm += bf16f(XH[idx]) + bf16f(XL[idx]);
    }
    xm[tid] = sm * (1.f / 128.f);
    __syncthreads();
    if (tid < 128) {
        float a = B1[tid];
        for (int k = 0; k < CDIM; ++k) a = fmaf(xm[k], W1[k * 128 + tid], a);
        a = fmaxf(a, 0.f);
        hred[tid] = a * W2[tid];
    }
    __syncthreads();
    for (int off = 64; off > 0; off >>= 1) {
        if (tid < off) hred[tid] += hred[tid + off];
        __syncthreads();
    }
    if (tid == 0) OUT[b] = hred[0] + B2[0];
}

// ---------------------------------------------------------------------------
extern "C" void kernel_launch(void* const* d_in, const int* in_sizes, int n_in,
                              void* d_out, int out_size, void* d_ws, size_t ws_size,
                              hipStream_t stream) {
    const float* RW  = (const float*)d_in[0];
    const float* POS = (const float*)d_in[1];
    const float* CW1 = (const float*)d_in[2];
    const float* CB1 = (const float*)d_in[3];
    const float* CW2 = (const float*)d_in[4];
    const float* CB2 = (const float*)d_in[5];

    const size_t NTOK = (size_t)NSEQ * SEQN * CDIM;  // 15.7M
    const size_t QN = (size_t)768 * 256, PN = (size_t)256 * 256;
    const size_t LSTRIDE = 2 * QN + 2 * PN;
    unsigned short* OH = (unsigned short*)d_ws;       // 31.5 MB
    unsigned short* XH = OH + NTOK;                   // 31.5 MB
    unsigned short* XL = XH + NTOK;                   // 31.5 MB
    unsigned short* WBUF = XL + NTOK;                 // 2 layers x 1.05 MB

    prep_kernel<<<dim3(NSEQ, 4, 8), 256, 0, stream>>>(RW, POS, XH, XL);
    wsplit_all_kernel<<<dim3(8, 64), 256, 0, stream>>>(
        (const float*)d_in[6], (const float*)d_in[8],
        (const float*)d_in[12], (const float*)d_in[14], WBUF);

    for (int li = 0; li < 2; ++li) {
        const float* qb = (const float*)d_in[7 + 6 * li];
        const float* pb = (const float*)d_in[9 + 6 * li];
        const float* lg = (const float*)d_in[10 + 6 * li];
        const float* lb = (const float*)d_in[11 + 6 * li];
        unsigned short* WtHi = WBUF + li * LSTRIDE;
        unsigned short* WtLo = WtHi + QN;
        unsigned short* W2H = WtHi + 2 * QN;
        unsigned short* W2L = W2H + PN;
        attn_kernel<<<NSEQ * NH, 256, 0, stream>>>(XH, XL, OH, WtHi, WtLo, qb);
        projln_kernel<<<dim3(NSEQ, 4), 256, 0, stream>>>(OH, XH, XL, W2H, W2L, pb, lg, lb);
    }

    cls_kernel<<<NSEQ, 256, 0, stream>>>(XH, XL, CW1, CB1, CW2, CB2, (float*)d_out);
}

// Round 11
// 725.293 us; speedup vs baseline: 1.6657x; 1.0293x over previous
//
#include <hip/hip_runtime.h>
#include <hip/hip_bf16.h>
#include <cmath>

#define NSEQ 480
#define SEQN 128
#define CDIM 256
#define NH 8
#define HD 32
#define TOPM 20

typedef float f32x4 __attribute__((ext_vector_type(4)));
typedef short bf16x8 __attribute__((ext_vector_type(8)));

__device__ __forceinline__ unsigned short bf16_rn(float x) {
    unsigned int u = __float_as_uint(x);
    unsigned int r = (u + 0x7FFFu + ((u >> 16) & 1u)) >> 16;
    return (unsigned short)r;
}
__device__ __forceinline__ float bf16f(unsigned short h) {
    return __uint_as_float(((unsigned int)h) << 16);
}
__device__ __forceinline__ unsigned pk_bf16(float a, float b) {
    union { __hip_bfloat162 h; unsigned u; } cv;
    cv.h = __float22bfloat162_rn(make_float2(a, b));
    return cv.u;
}
__device__ __forceinline__ void unpack_bf16x8(uint4 u, float* o) {
    o[0] = bf16f((unsigned short)(u.x & 0xffffu)); o[1] = bf16f((unsigned short)(u.x >> 16));
    o[2] = bf16f((unsigned short)(u.y & 0xffffu)); o[3] = bf16f((unsigned short)(u.y >> 16));
    o[4] = bf16f((unsigned short)(u.z & 0xffffu)); o[5] = bf16f((unsigned short)(u.z >> 16));
    o[6] = bf16f((unsigned short)(u.w & 0xffffu)); o[7] = bf16f((unsigned short)(u.w >> 16));
}
// one ulp above x (x finite); used as exclusive upper bisection bound
__device__ __forceinline__ float ulp_above(float x) {
    x = x + 0.0f;  // -0 -> +0
    unsigned u = __float_as_uint(x);
    u = (x >= 0.f) ? u + 1u : u - 1u;
    return __uint_as_float(u);
}

// ---------------------------------------------------------------------------
// K1: transpose (B, C, N) -> (B, N, C), add pos_embed, emit split-bf16 planes.
__global__ __launch_bounds__(256) void prep_kernel(const float* __restrict__ RW,
                                                   const float* __restrict__ POS,
                                                   unsigned short* __restrict__ XH,
                                                   unsigned short* __restrict__ XL) {
    int b = blockIdx.x, n0 = blockIdx.y * 32, c0 = blockIdx.z * 32;
    __shared__ float tile[32][33];
    int tx = threadIdx.x & 31, ty = threadIdx.x >> 5;
#pragma unroll
    for (int jj = 0; jj < 4; ++jj) {
        int c = c0 + ty + 8 * jj;
        tile[ty + 8 * jj][tx] = RW[((size_t)b * CDIM + c) * SEQN + n0 + tx];
    }
    __syncthreads();
    const int cp = threadIdx.x & 15;
    const int nr = threadIdx.x >> 4;
#pragma unroll
    for (int pass = 0; pass < 2; ++pass) {
        int n = n0 + nr + 16 * pass;
        int c = c0 + cp * 2;
        const float* prow = POS + (size_t)n * CDIM + c;
        float v0 = tile[cp * 2 + 0][nr + 16 * pass] + prow[0];
        float v1 = tile[cp * 2 + 1][nr + 16 * pass] + prow[1];
        unsigned short h0 = bf16_rn(v0), h1 = bf16_rn(v1);
        unsigned short l0 = bf16_rn(v0 - bf16f(h0)), l1 = bf16_rn(v1 - bf16f(h1));
        size_t widx = ((size_t)b * SEQN * CDIM + (size_t)n * CDIM + c) >> 1;
        reinterpret_cast<unsigned*>(XH)[widx] = (unsigned)h0 | ((unsigned)h1 << 16);
        reinterpret_cast<unsigned*>(XL)[widx] = (unsigned)l0 | ((unsigned)l1 << 16);
    }
}

// ---------------------------------------------------------------------------
// K1b: ALL weight splits (both layers) in one launch.
__global__ __launch_bounds__(256) void wsplit_all_kernel(
    const float* __restrict__ Wq0, const float* __restrict__ Wp0,
    const float* __restrict__ Wq1, const float* __restrict__ Wp1,
    unsigned short* __restrict__ WBUF) {
    int k0 = blockIdx.x * 32;
    int yy = blockIdx.y;
    int li = yy >> 5;
    int ys = yy & 31;
    const size_t QN = (size_t)768 * 256, PN = (size_t)256 * 256;
    const size_t LSTRIDE = 2 * QN + 2 * PN;
    unsigned short* base = WBUF + li * LSTRIDE;
    const float* W;
    unsigned short *WH, *WL;
    int ncols, j0;
    if (ys < 24) {
        W = li ? Wq1 : Wq0; WH = base; WL = base + QN; ncols = 768; j0 = ys * 32;
    } else {
        W = li ? Wp1 : Wp0; WH = base + 2 * QN; WL = base + 2 * QN + PN; ncols = 256; j0 = (ys - 24) * 32;
    }
    __shared__ float tile[32][33];
    int tx = threadIdx.x & 31, ty = threadIdx.x >> 5;
#pragma unroll
    for (int jj = 0; jj < 4; ++jj)
        tile[ty + 8 * jj][tx] = W[(size_t)(k0 + ty + 8 * jj) * ncols + j0 + tx];
    __syncthreads();
#pragma unroll
    for (int jj = 0; jj < 4; ++jj) {
        float v = tile[tx][ty + 8 * jj];
        unsigned short hi = bf16_rn(v);
        unsigned short lo = bf16_rn(v - bf16f(hi));
        size_t idx = (size_t)(j0 + ty + 8 * jj) * 256 + k0 + tx;
        WH[idx] = hi;
        WL[idx] = lo;
    }
}

// ---------------------------------------------------------------------------
// K2: fused qkv + exact top-20 attention (round-5 structure).
// Selection: FLOAT-domain bracketed bisection (value-scale convergence),
// exact w.r.t. computed scores incl. ties; softmax via exp2 with log2e
// folded into the q scale (order/mask/values unchanged).
__global__ __launch_bounds__(256, 4) void attn_kernel(
    const unsigned short* __restrict__ XHi, const unsigned short* __restrict__ XLo,
    unsigned short* __restrict__ OH,
    const unsigned short* __restrict__ WtHi, const unsigned short* __restrict__ WtLo,
    const float* __restrict__ BIAS) {
    const int bid = blockIdx.x;
    const int h = (bid >> 3) & 7;
    const int b = ((bid >> 6) << 3) | (bid & 7);
    const float scale2 = 0.25503486f;  // (1/sqrt(32)) * log2(e)

    __shared__ unsigned short qh[SEQN * HD], ql[SEQN * HD];
    __shared__ unsigned short kh[SEQN * HD], kl[SEQN * HD];
    __shared__ unsigned short vh[HD * SEQN];

    const int tid = threadIdx.x;
    const int w = tid >> 6;
    const int l = tid & 63;
    const int l15 = l & 15;
    const int sct = l >> 4;
    const size_t xbase = (size_t)b * SEQN * CDIM;

    // ================= Phase 1: QKV via MFMA =================
    f32x4 acc[2][6];  // ni 0,1=q  2,3=k  4,5=v
#pragma unroll
    for (int mi = 0; mi < 2; ++mi)
#pragma unroll
        for (int ni = 0; ni < 6; ++ni) acc[mi][ni] = (f32x4){0.f, 0.f, 0.f, 0.f};

#pragma unroll 2
    for (int ks = 0; ks < 8; ++ks) {
        const int kb = ks * 32;
        bf16x8 ahi[2], alo[2];
#pragma unroll
        for (int mi = 0; mi < 2; ++mi) {
            int row = w * 32 + mi * 16 + l15;
            size_t off = xbase + row * CDIM + kb + sct * 8;
            ahi[mi] = *reinterpret_cast<const bf16x8*>(XHi + off);
            alo[mi] = *reinterpret_cast<const bf16x8*>(XLo + off);
        }
#pragma unroll
        for (int ni = 0; ni < 6; ++ni) {
            int j = ((ni >> 1) << 8) + h * HD + ((ni & 1) << 4) + l15;
            const int woff = j * 256 + kb + sct * 8;
            bf16x8 bh = *reinterpret_cast<const bf16x8*>(WtHi + woff);
            if (ni < 4) {
                bf16x8 bl = *reinterpret_cast<const bf16x8*>(WtLo + woff);
#pragma unroll
                for (int mi = 0; mi < 2; ++mi) {
                    acc[mi][ni] = __builtin_amdgcn_mfma_f32_16x16x32_bf16(ahi[mi], bh, acc[mi][ni], 0, 0, 0);
                    acc[mi][ni] = __builtin_amdgcn_mfma_f32_16x16x32_bf16(ahi[mi], bl, acc[mi][ni], 0, 0, 0);
                    acc[mi][ni] = __builtin_amdgcn_mfma_f32_16x16x32_bf16(alo[mi], bh, acc[mi][ni], 0, 0, 0);
                }
            } else {
#pragma unroll
                for (int mi = 0; mi < 2; ++mi)
                    acc[mi][ni] = __builtin_amdgcn_mfma_f32_16x16x32_bf16(ahi[mi], bh, acc[mi][ni], 0, 0, 0);
            }
        }
    }
#pragma unroll
    for (int ni = 0; ni < 6; ++ni) {
        const int sel = ni >> 1;
        const int dcol = ((ni & 1) << 4) + l15;
        const float bias = BIAS[(sel << 8) + h * HD + dcol];
#pragma unroll
        for (int mi = 0; mi < 2; ++mi) {
            const int tb = w * 32 + mi * 16 + sct * 4;
            if (sel == 2) {
                float v0 = acc[mi][ni][0] + bias, v1 = acc[mi][ni][1] + bias;
                float v2 = acc[mi][ni][2] + bias, v3 = acc[mi][ni][3] + bias;
                unsigned pA = pk_bf16(v0, v1), pB = pk_bf16(v2, v3);
                int c0i = tb ^ ((dcol & 7) << 3);
                *reinterpret_cast<uint2*>(&vh[dcol * SEQN + c0i]) = make_uint2(pA, pB);
            } else {
                unsigned short* ph = sel ? kh : qh;
                unsigned short* pl = sel ? kl : ql;
#pragma unroll
                for (int r = 0; r < 4; ++r) {
                    float v = acc[mi][ni][r] + bias;
                    if (sel == 0) v *= scale2;
                    unsigned short hi = bf16_rn(v);
                    int token = tb + r;
                    int idx = token * HD + (dcol ^ (((token >> 1) & 3) << 3));
                    ph[idx] = hi;
                    pl[idx] = bf16_rn(v - bf16f(hi));
                }
            }
        }
    }
    __syncthreads();

    // ================= Phase 2: S^T = K·Q^T, in-register softmax ============
    f32x4 sacc[8][2];
#pragma unroll
    for (int mi = 0; mi < 8; ++mi)
#pragma unroll
        for (int ni = 0; ni < 2; ++ni) sacc[mi][ni] = (f32x4){0.f, 0.f, 0.f, 0.f};

    bf16x8 qfh[2], qfl[2];
#pragma unroll
    for (int ni = 0; ni < 2; ++ni) {
        int qrow = w * 32 + (ni << 4) + l15;
        int off = qrow * HD + ((sct * 8) ^ (((qrow >> 1) & 3) << 3));
        qfh[ni] = *reinterpret_cast<const bf16x8*>(qh + off);
        qfl[ni] = *reinterpret_cast<const bf16x8*>(ql + off);
    }
    __builtin_amdgcn_s_setprio(1);
#pragma unroll
    for (int mi = 0; mi < 8; ++mi) {
        int krow = (mi << 4) + l15;
        int off = krow * HD + ((sct * 8) ^ (((krow >> 1) & 3) << 3));
        bf16x8 kfh = *reinterpret_cast<const bf16x8*>(kh + off);
        bf16x8 kfl = *reinterpret_cast<const bf16x8*>(kl + off);
#pragma unroll
        for (int ni = 0; ni < 2; ++ni) {
            sacc[mi][ni] = __builtin_amdgcn_mfma_f32_16x16x32_bf16(kfh, qfh[ni], sacc[mi][ni], 0, 0, 0);
            sacc[mi][ni] = __builtin_amdgcn_mfma_f32_16x16x32_bf16(kfh, qfl[ni], sacc[mi][ni], 0, 0, 0);
            sacc[mi][ni] = __builtin_amdgcn_mfma_f32_16x16x32_bf16(kfl, qfh[ni], sacc[mi][ni], 0, 0, 0);
        }
    }
    __builtin_amdgcn_s_setprio(0);

    // row max and min (float domain, 4 lanes per row: xor 16, 32)
    float mx0 = sacc[0][0][0], mn0 = sacc[0][0][0];
    float mx1 = sacc[0][1][0], mn1 = sacc[0][1][0];
#pragma unroll
    for (int mi = 0; mi < 8; ++mi)
#pragma unroll
        for (int r = 0; r < 4; ++r) {
            float u0 = sacc[mi][0][r], u1 = sacc[mi][1][r];
            mx0 = fmaxf(mx0, u0); mn0 = fminf(mn0, u0);
            mx1 = fmaxf(mx1, u1); mn1 = fminf(mn1, u1);
        }
    mx0 = fmaxf(mx0, __shfl_xor(mx0, 16));
    mx0 = fmaxf(mx0, __shfl_xor(mx0, 32));
    mx1 = fmaxf(mx1, __shfl_xor(mx1, 16));
    mx1 = fmaxf(mx1, __shfl_xor(mx1, 32));
    mn0 = fminf(mn0, __shfl_xor(mn0, 16));
    mn0 = fminf(mn0, __shfl_xor(mn0, 32));
    mn1 = fminf(mn1, __shfl_xor(mn1, 16));
    mn1 = fminf(mn1, __shfl_xor(mn1, 32));

    // exact top-20 threshold per q-row: FLOAT bisection on [mn, ulp_above(mx)).
    // invariants: count(lo) >= TOPM, count(hi) < TOPM.  Early exit at c==TOPM
    // (mask == top-20 exactly); terminal 1-ulp bracket -> thr = kth (ties ok).
    float p0f, p1f;
    {
        float lo0 = mn0, hi0 = ulp_above(mx0), lo1 = mn1, hi1 = ulp_above(mx1);
        float th0 = mx0, th1 = mx1;
        int dn0 = 0, dn1 = 0;
#pragma unroll 1
        for (int it = 0; it < 48; ++it) {
            if (__all(dn0 & dn1)) break;
            float mid0 = 0.5f * (lo0 + hi0);
            float mid1 = 0.5f * (lo1 + hi1);
            int c0 = 0, c1 = 0;
#pragma unroll
            for (int mi = 0; mi < 8; ++mi)
#pragma unroll
                for (int r = 0; r < 4; ++r) {
                    c0 += (sacc[mi][0][r] >= mid0) ? 1 : 0;
                    c1 += (sacc[mi][1][r] >= mid1) ? 1 : 0;
                }
            int mpk = c0 | (c1 << 8);
            mpk += __shfl_xor(mpk, 16);
            mpk += __shfl_xor(mpk, 32);
            c0 = mpk & 255;
            c1 = mpk >> 8;
            if (!dn0) {
                if (c0 == TOPM) { th0 = mid0; dn0 = 1; }
                else if (mid0 <= lo0 || mid0 >= hi0) { th0 = lo0; dn0 = 1; }
                else if (c0 > TOPM) lo0 = mid0;
                else hi0 = mid0;
            }
            if (!dn1) {
                if (c1 == TOPM) { th1 = mid1; dn1 = 1; }
                else if (mid1 <= lo1 || mid1 >= hi1) { th1 = lo1; dn1 = 1; }
                else if (c1 > TOPM) lo1 = mid1;
                else hi1 = mid1;
            }
        }
        p0f = th0; p1f = th1;
    }

    // masked exp2 (scores are pre-scaled by log2e) + row sums
    float s0 = 0.f, s1 = 0.f;
#pragma unroll
    for (int mi = 0; mi < 8; ++mi)
#pragma unroll
        for (int r = 0; r < 4; ++r) {
            float v0 = sacc[mi][0][r], v1 = sacc[mi][1][r];
            float e0 = (v0 >= p0f) ? exp2f(v0 - mx0) : 0.f;
            float e1 = (v1 >= p1f) ? exp2f(v1 - mx1) : 0.f;
            sacc[mi][0][r] = e0;
            sacc[mi][1][r] = e1;
            s0 += e0;
            s1 += e1;
        }
    s0 += __shfl_xor(s0, 16);
    s0 += __shfl_xor(s0, 32);
    s1 += __shfl_xor(s1, 16);
    s1 += __shfl_xor(s1, 32);
    float i0 = 1.f / s0, i1 = 1.f / s1;

    // ================= Phase 3: O = P·V via MFMA (per-k weight pack) ========
    f32x4 oacc[2][2];
#pragma unroll
    for (int mi = 0; mi < 2; ++mi)
#pragma unroll
        for (int ni = 0; ni < 2; ++ni) oacc[mi][ni] = (f32x4){0.f, 0.f, 0.f, 0.f};

#pragma unroll
    for (int k = 0; k < 4; ++k) {
        unsigned w16k[2][2][2];  // [mi-offset][ni][pair]
#pragma unroll
        for (int m2 = 0; m2 < 2; ++m2)
#pragma unroll
            for (int ni = 0; ni < 2; ++ni)
#pragma unroll
                for (int p = 0; p < 2; ++p)
                    w16k[m2][ni][p] = pk_bf16(sacc[2 * k + m2][ni][2 * p], sacc[2 * k + m2][ni][2 * p + 1]);
        bf16x8 bvh[2];
#pragma unroll
        for (int nio = 0; nio < 2; ++nio) {
            int drow = (nio << 4) + l15;
            int off = drow * SEQN + ((k * 32 + sct * 8) ^ ((drow & 7) << 3));
            bvh[nio] = *reinterpret_cast<const bf16x8*>(vh + off);
        }
#pragma unroll
        for (int mio = 0; mio < 2; ++mio) {
            union { unsigned u[4]; bf16x8 v8; } aw;
#pragma unroll
            for (int j = 0; j < 4; ++j) {
                int src = l15 + ((sct & 1) << 5) + ((j >> 1) << 4);
                unsigned a0 = (unsigned)__shfl((int)w16k[0][mio][j & 1], src);
                unsigned a1 = (unsigned)__shfl((int)w16k[1][mio][j & 1], src);
                aw.u[j] = (sct >= 2) ? a1 : a0;
            }
            __builtin_amdgcn_s_setprio(1);
#pragma unroll
            for (int nio = 0; nio < 2; ++nio)
                oacc[mio][nio] = __builtin_amdgcn_mfma_f32_16x16x32_bf16(aw.v8, bvh[nio], oacc[mio][nio], 0, 0, 0);
            __builtin_amdgcn_s_setprio(0);
        }
    }
    float invO[2][4];
#pragma unroll
    for (int mio = 0; mio < 2; ++mio)
#pragma unroll
        for (int r = 0; r < 4; ++r)
            invO[mio][r] = __shfl(mio ? i1 : i0, sct * 4 + r);
#pragma unroll
    for (int mio = 0; mio < 2; ++mio)
#pragma unroll
        for (int nio = 0; nio < 2; ++nio)
#pragma unroll
            for (int r = 0; r < 4; ++r) {
                int token = w * 32 + mio * 16 + sct * 4 + r;
                int d = (nio << 4) + l15;
                size_t idx = ((size_t)b * SEQN + token) * CDIM + h * HD + d;
                OH[idx] = bf16_rn(oacc[mio][nio][r] * invO[mio][r]);
            }
}

// ---------------------------------------------------------------------------
// K3: MFMA proj GEMM (A = single-bf16 O, B split -> 2-term) + bias + residual
// + LayerNorm, 32 tokens per block.  grid (480, 4), block 256.
__global__ __launch_bounds__(256, 4) void projln_kernel(
    const unsigned short* __restrict__ OHp,
    unsigned short* __restrict__ XH, unsigned short* __restrict__ XL,
    const unsigned short* __restrict__ W2H, const unsigned short* __restrict__ W2L,
    const float* __restrict__ PB, const float* __restrict__ G,
    const float* __restrict__ BB) {
    const int b = blockIdx.x;
    const int t0 = blockIdx.y * 32;
    __shared__ float vals[32 * 289];
    __shared__ float part[8][32][2];

    const int tid = threadIdx.x;
    const int w = tid >> 6;
    const int l = tid & 63;
    const int l15 = l & 15;
    const int sct = l >> 4;

    f32x4 acc[2][4];
#pragma unroll
    for (int mi = 0; mi < 2; ++mi)
#pragma unroll
        for (int ni = 0; ni < 4; ++ni) acc[mi][ni] = (f32x4){0.f, 0.f, 0.f, 0.f};

    const size_t obase = ((size_t)b * SEQN + t0) * CDIM;
#pragma unroll 2
    for (int ks = 0; ks < 8; ++ks) {
        const int kb = ks * 32;
        bf16x8 ahi[2];
#pragma unroll
        for (int mi = 0; mi < 2; ++mi) {
            size_t off = obase + (size_t)(mi * 16 + l15) * CDIM + kb + sct * 8;
            ahi[mi] = *reinterpret_cast<const bf16x8*>(OHp + off);
        }
#pragma unroll
        for (int ni = 0; ni < 4; ++ni) {
            int j = w * 64 + ni * 16 + l15;
            int woff = j * 256 + kb + sct * 8;
            bf16x8 bh = *reinterpret_cast<const bf16x8*>(W2H + woff);
            bf16x8 bl = *reinterpret_cast<const bf16x8*>(W2L + woff);
#pragma unroll
            for (int mi = 0; mi < 2; ++mi) {
                acc[mi][ni] = __builtin_amdgcn_mfma_f32_16x16x32_bf16(ahi[mi], bh, acc[mi][ni], 0, 0, 0);
                acc[mi][ni] = __builtin_amdgcn_mfma_f32_16x16x32_bf16(ahi[mi], bl, acc[mi][ni], 0, 0, 0);
            }
        }
    }
#pragma unroll
    for (int ni = 0; ni < 4; ++ni) {
        int j = w * 64 + ni * 16 + l15;
        float bias = PB[j];
#pragma unroll
        for (int mi = 0; mi < 2; ++mi)
#pragma unroll
            for (int r = 0; r < 4; ++r) {
                int tok = mi * 16 + sct * 4 + r;
                vals[tok * 289 + j] = acc[mi][ni][r] + bias;
            }
    }
    __syncthreads();

    const int row = tid & 31;
    const int cc = tid >> 5;
    const size_t rbase = ((size_t)b * SEQN + t0 + row) * CDIM + cc * 32;
    float v[32];
    {
        float ps = 0.f, pq = 0.f;
#pragma unroll
        for (int q = 0; q < 4; ++q) {
            uint4 hb = *reinterpret_cast<const uint4*>(XH + rbase + q * 8);
            uint4 lb = *reinterpret_cast<const uint4*>(XL + rbase + q * 8);
            float rh[8], rl[8];
            unpack_bf16x8(hb, rh);
            unpack_bf16x8(lb, rl);
#pragma unroll
            for (int jj = 0; jj < 8; ++jj) {
                int col = cc * 32 + q * 8 + jj;
                float val = vals[row * 289 + col] + rh[jj] + rl[jj];
                v[q * 8 + jj] = val;
                ps += val;
                pq = fmaf(val, val, pq);
            }
        }
        part[cc][row][0] = ps;
        part[cc][row][1] = pq;
    }
    __syncthreads();
    float s1 = 0.f, s2 = 0.f;
#pragma unroll
    for (int k = 0; k < 8; ++k) { s1 += part[k][row][0]; s2 += part[k][row][1]; }
    float m = s1 * (1.f / 256.f);
    float var = s2 * (1.f / 256.f) - m * m;
    float rstd = rsqrtf(var + 1e-5f);
#pragma unroll
    for (int q = 0; q < 4; ++q) {
        int col0 = cc * 32 + q * 8;
        float4 g0 = *reinterpret_cast<const float4*>(G + col0);
        float4 g1 = *reinterpret_cast<const float4*>(G + col0 + 4);
        float4 b0 = *reinterpret_cast<const float4*>(BB + col0);
        float4 b1 = *reinterpret_cast<const float4*>(BB + col0 + 4);
        float gg[8] = {g0.x, g0.y, g0.z, g0.w, g1.x, g1.y, g1.z, g1.w};
        float bb2[8] = {b0.x, b0.y, b0.z, b0.w, b1.x, b1.y, b1.z, b1.w};
        unsigned hw[4], lw[4];
#pragma unroll
        for (int p2 = 0; p2 < 4; ++p2) {
            float y0 = (v[q * 8 + p2 * 2] - m) * rstd * gg[p2 * 2] + bb2[p2 * 2];
            float y1 = (v[q * 8 + p2 * 2 + 1] - m) * rstd * gg[p2 * 2 + 1] + bb2[p2 * 2 + 1];
            unsigned short h0 = bf16_rn(y0), h1 = bf16_rn(y1);
            unsigned short lo0 = bf16_rn(y0 - bf16f(h0)), lo1 = bf16_rn(y1 - bf16f(h1));
            hw[p2] = (unsigned)h0 | ((unsigned)h1 << 16);
            lw[p2] = (unsigned)lo0 | ((unsigned)lo1 << 16);
        }
        *reinterpret_cast<uint4*>(XH + rbase + q * 8) = make_uint4(hw[0], hw[1], hw[2], hw[3]);
        *reinterpret_cast<uint4*>(XL + rbase + q * 8) = make_uint4(lw[0], lw[1], lw[2], lw[3]);
    }
}

// ---------------------------------------------------------------------------
// K4: mean over tokens + classifier head (reads planes). grid 480, block 256.
__global__ __launch_bounds__(256) void cls_kernel(const unsigned short* __restrict__ XH,
                                                  const unsigned short* __restrict__ XL,
                                                  const float* __restrict__ W1,
                                                  const float* __restrict__ B1,
                                                  const float* __restrict__ W2,
                                                  const float* __restrict__ B2,
                                                  float* __restrict__ OUT) {
    int b = blockIdx.x;
    __shared__ float xm[256];
    __shared__ float hred[128];
    int tid = threadIdx.x;
    float sm = 0.f;
    for (int n = 0; n < SEQN; ++n) {
        size_t idx = ((size_t)b * SEQN + n) * CDIM + tid;
        sm += bf16f(XH[idx]) + bf16f(XL[idx]);
    }
    xm[tid] = sm * (1.f / 128.f);
    __syncthreads();
    if (tid < 128) {
        float a = B1[tid];
        for (int k = 0; k < CDIM; ++k) a = fmaf(xm[k], W1[k * 128 + tid], a);
        a = fmaxf(a, 0.f);
        hred[tid] = a * W2[tid];
    }
    __syncthreads();
    for (int off = 64; off > 0; off >>= 1) {
        if (tid < off) hred[tid] += hred[tid + off];
        __syncthreads();
    }
    if (tid == 0) OUT[b] = hred[0] + B2[0];
}

// ---------------------------------------------------------------------------
extern "C" void kernel_launch(void* const* d_in, const int* in_sizes, int n_in,
                              void* d_out, int out_size, void* d_ws, size_t ws_size,
                              hipStream_t stream) {
    const float* RW  = (const float*)d_in[0];
    const float* POS = (const float*)d_in[1];
    const float* CW1 = (const float*)d_in[2];
    const float* CB1 = (const float*)d_in[3];
    const float* CW2 = (const float*)d_in[4];
    const float* CB2 = (const float*)d_in[5];

    const size_t NTOK = (size_t)NSEQ * SEQN * CDIM;  // 15.7M
    const size_t QN = (size_t)768 * 256, PN = (size_t)256 * 256;
    const size_t LSTRIDE = 2 * QN + 2 * PN;
    unsigned short* OH = (unsigned short*)d_ws;       // 31.5 MB
    unsigned short* XH = OH + NTOK;                   // 31.5 MB
    unsigned short* XL = XH + NTOK;                   // 31.5 MB
    unsigned short* WBUF = XL + NTOK;                 // 2 layers x 1.05 MB

    prep_kernel<<<dim3(NSEQ, 4, 8), 256, 0, stream>>>(RW, POS, XH, XL);
    wsplit_all_kernel<<<dim3(8, 64), 256, 0, stream>>>(
        (const float*)d_in[6], (const float*)d_in[8],
        (const float*)d_in[12], (const float*)d_in[14], WBUF);

    for (int li = 0; li < 2; ++li) {
        const float* qb = (const float*)d_in[7 + 6 * li];
        const float* pb = (const float*)d_in[9 + 6 * li];
        const float* lg = (const float*)d_in[10 + 6 * li];
        const float* lb = (const float*)d_in[11 + 6 * li];
        unsigned short* WtHi = WBUF + li * LSTRIDE;
        unsigned short* WtLo = WtHi + QN;
        unsigned short* W2H = WtHi + 2 * QN;
        unsigned short* W2L = W2H + PN;
        attn_kernel<<<NSEQ * NH, 256, 0, stream>>>(XH, XL, OH, WtHi, WtLo, qb);
        projln_kernel<<<dim3(NSEQ, 4), 256, 0, stream>>>(OH, XH, XL, W2H, W2L, pb, lg, lb);
    }

    cls_kernel<<<NSEQ, 256, 0, stream>>>(XH, XL, CW1, CB1, CW2, CB2, (float*)d_out);
}